// Round 5
// baseline (1432.730 us; speedup 1.0000x reference)
//
#include <hip/hip_runtime.h>
#include <stdint.h>

#pragma clang fp contract(off)

#define B 8
#define N 65536
#define KC 64        // clusters
#define M 128        // neighbors per center (NPOINT/K*2)
#define S 64         // fps samples per group (NPOINT/K)
#define NITER 10
#define CHUNK 256
#define NCHUNK (N / CHUNK)   // 256
#define SUMCHUNK 2048        // points staged in LDS per pass in k_sum_divide

using u32 = unsigned int;
using u64 = unsigned long long;

// ---- exact fp32 helpers (no FMA contraction, fixed association) ----
__device__ __forceinline__ float sq3(float a, float b, float c) {
  return __fadd_rn(__fadd_rn(__fmul_rn(a, a), __fmul_rn(b, b)), __fmul_rn(c, c));
}
__device__ __forceinline__ float dot3(float x0, float x1, float x2,
                                      float c0, float c1, float c2) {
  return __fadd_rn(__fadd_rn(__fmul_rn(x0, c0), __fmul_rn(x1, c1)), __fmul_rn(x2, c2));
}
__device__ __forceinline__ float distf(float s2, float d2, float dt) {
  // (s2 + d2) - 2*dot   — matches reference op order
  return __fsub_rn(__fadd_rn(s2, d2), __fmul_rn(2.0f, dt));
}
// monotone float->uint key (total order preserving)
__device__ __forceinline__ u32 fkey(float f) {
  u32 u = __float_as_uint(f);
  return (u & 0x80000000u) ? ~u : (u | 0x80000000u);
}

// ---- kernels ----

__global__ void k_init_centers(const float* __restrict__ x, float* __restrict__ centers) {
  int i = blockIdx.x * blockDim.x + threadIdx.x;
  if (i >= B * KC * 3) return;
  int b = i / (KC * 3);
  int r = i % (KC * 3);
  centers[i] = x[(size_t)b * N * 3 + r];   // c = x[:, :K, :]
}

__global__ void k_assign(const float* __restrict__ x, const float* __restrict__ centers,
                         unsigned char* __restrict__ cl, int* __restrict__ hist) {
  __shared__ float cx[KC], cy[KC], cz[KC], d2s[KC];
  __shared__ int lh[KC];
  int b = blockIdx.x >> 8;
  int chunk = blockIdx.x & 255;
  int t = threadIdx.x;
  if (t < KC) {
    float a0 = centers[(b * KC + t) * 3 + 0];
    float a1 = centers[(b * KC + t) * 3 + 1];
    float a2 = centers[(b * KC + t) * 3 + 2];
    cx[t] = a0; cy[t] = a1; cz[t] = a2;
    d2s[t] = sq3(a0, a1, a2);
    lh[t] = 0;
  }
  __syncthreads();
  int n = chunk * CHUNK + t;
  size_t xb = ((size_t)b * N + n) * 3;
  float x0 = x[xb], x1 = x[xb + 1], x2 = x[xb + 2];
  float s2 = sq3(x0, x1, x2);
  float best = __int_as_float(0x7f800000);  // +inf
  int bi = 0;
  for (int k = 0; k < KC; ++k) {
    float dt = dot3(x0, x1, x2, cx[k], cy[k], cz[k]);
    float d = distf(s2, d2s[k], dt);
    if (d < best) { best = d; bi = k; }     // first-min tie-break == argmin
  }
  cl[(size_t)b * N + n] = (unsigned char)bi;
  atomicAdd(&lh[bi], 1);
  __syncthreads();
  if (t < KC) hist[((b * NCHUNK) + chunk) * KC + t] = lh[t];
}

__global__ void k_scan_chunks(const int* __restrict__ hist, int* __restrict__ chunkOff,
                              int* __restrict__ totals) {
  int gt = blockIdx.x * blockDim.x + threadIdx.x;
  if (gt >= B * KC) return;
  int b = gt >> 6, k = gt & 63;
  int run = 0;
  for (int c = 0; c < NCHUNK; ++c) {
    int idx = ((b * NCHUNK) + c) * KC + k;
    chunkOff[idx] = run;
    run += hist[idx];
  }
  totals[gt] = run;
}

__global__ void k_batch_prefix(const int* __restrict__ totals, int* __restrict__ kBase) {
  int b = threadIdx.x;
  if (b >= B) return;
  int base = 0;
  for (int k = 0; k < KC; ++k) { kBase[b * KC + k] = base; base += totals[b * KC + k]; }
}

// stable counting-sort scatter: writes point coords grouped by cluster, in
// increasing original index order within each cluster (matches np.add.at order)
__global__ void k_scatter(const float* __restrict__ x, const unsigned char* __restrict__ cl,
                          const int* __restrict__ chunkOff, const int* __restrict__ kBase,
                          float* __restrict__ sortedPts) {
  __shared__ unsigned char lcl[CHUNK];
  int b = blockIdx.x >> 8, chunk = blockIdx.x & 255, t = threadIdx.x;
  int n = chunk * CHUNK + t;
  lcl[t] = cl[(size_t)b * N + n];
  __syncthreads();
  int k = lcl[t];
  int rank = 0;
  for (int j = 0; j < t; ++j) rank += (lcl[j] == k);
  int pos = kBase[b * KC + k] + chunkOff[((b * NCHUNK) + chunk) * KC + k] + rank;
  size_t src = ((size_t)b * N + n) * 3;
  size_t dst = ((size_t)b * N + pos) * 3;
  sortedPts[dst]     = x[src];
  sortedPts[dst + 1] = x[src + 1];
  sortedPts[dst + 2] = x[src + 2];
}

// one block per (b,k): cooperative LDS staging, lane 0 does the strictly
// sequential fp32 sum in original index order (bit-identical to np.add.at)
__global__ void k_sum_divide(const float* __restrict__ sortedPts,
                             const int* __restrict__ kBase, const int* __restrict__ totals,
                             float* __restrict__ centers) {
  __shared__ float buf[3 * SUMCHUNK];
  int gt = blockIdx.x;         // b*KC + k
  int b = gt >> 6;
  int t = threadIdx.x;
  int off = kBase[gt], cnt = totals[gt];
  const float* sp = sortedPts + ((size_t)b * N + off) * 3;
  float sx = 0.f, sy = 0.f, sz = 0.f;
  for (int base = 0; base < cnt; base += SUMCHUNK) {
    int m = min(SUMCHUNK, cnt - base);
    int nf = m * 3;
    for (int i = t; i < nf; i += 256) buf[i] = sp[(size_t)base * 3 + i];
    __syncthreads();
    if (t == 0) {
#pragma unroll 4
      for (int i = 0; i < m; ++i) {
        sx = __fadd_rn(sx, buf[3 * i]);
        sy = __fadd_rn(sy, buf[3 * i + 1]);
        sz = __fadd_rn(sz, buf[3 * i + 2]);
      }
    }
    __syncthreads();
  }
  if (t == 0) {
    float fc = (float)cnt;
    centers[gt * 3 + 0] = __fdiv_rn(sx, fc);
    centers[gt * 3 + 1] = __fdiv_rn(sy, fc);
    centers[gt * 3 + 2] = __fdiv_rn(sz, fc);
  }
}

// exact top-M (smallest distance, lower-index tiebreak) per (b,center)
// via 4-round byte radix-select on monotone keys + exact (key,idx) sort.
__global__ void k_query_topk(const float* __restrict__ x, const float* __restrict__ centers,
                             float* __restrict__ neighbor) {
  __shared__ u32 hist[256];
  __shared__ u64 lessList[M];
  __shared__ u32 eqList[256];
  __shared__ u32 sPrefix;
  __shared__ int sNeed;
  __shared__ int cntLess, cntEq;
  __shared__ float sc0, sc1, sc2, sd2;

  int bk = blockIdx.x;      // b*KC + k
  int b = bk >> 6;
  int t = threadIdx.x;
  if (t == 0) {
    float c0 = centers[bk * 3], c1 = centers[bk * 3 + 1], c2 = centers[bk * 3 + 2];
    sc0 = c0; sc1 = c1; sc2 = c2; sd2 = sq3(c0, c1, c2);
    cntLess = 0; cntEq = 0;
  }
  __syncthreads();
  float c0 = sc0, c1 = sc1, c2 = sc2, d2 = sd2;
  const float* xb = x + (size_t)b * N * 3;

  u32 prefix = 0;
  int need = M;
  for (int r = 3; r >= 0; --r) {
    for (int i = t; i < 256; i += 256) hist[i] = 0;
    __syncthreads();
    int sh = r * 8;
    for (int n = t; n < N; n += 256) {
      float x0 = xb[n * 3], x1 = xb[n * 3 + 1], x2 = xb[n * 3 + 2];
      float d = distf(sq3(x0, x1, x2), d2, dot3(x0, x1, x2, c0, c1, c2));
      u32 key = fkey(d);
      bool ok = (r == 3) || ((key >> (sh + 8)) == (prefix >> (sh + 8)));
      if (ok) atomicAdd(&hist[(key >> sh) & 255u], 1u);
    }
    __syncthreads();
    if (t == 0) {
      int cum = 0;
      for (int bin = 0; bin < 256; ++bin) {
        int c = (int)hist[bin];
        if (cum + c >= need) { sPrefix = prefix | ((u32)bin << sh); sNeed = need - cum; break; }
        cum += c;
      }
    }
    __syncthreads();
    prefix = sPrefix; need = sNeed;
    __syncthreads();
  }
  u32 K128 = prefix;   // exact key of the M-th smallest distance

  for (int n = t; n < N; n += 256) {
    float x0 = xb[n * 3], x1 = xb[n * 3 + 1], x2 = xb[n * 3 + 2];
    float d = distf(sq3(x0, x1, x2), d2, dot3(x0, x1, x2, c0, c1, c2));
    u32 key = fkey(d);
    if (key < K128) {
      int p = atomicAdd(&cntLess, 1);
      if (p < M) lessList[p] = ((u64)key << 32) | (u32)n;   // p < M guaranteed
    } else if (key == K128) {
      int p = atomicAdd(&cntEq, 1);
      if (p < 256) eqList[p] = (u32)n;
    }
  }
  __syncthreads();
  int nl = cntLess;   // < M by construction
  int ne = cntEq;
  for (int i = t; i < M; i += 256) if (i >= nl) lessList[i] = ~0ull;
  for (int i = t; i < 256; i += 256) if (i >= ne) eqList[i] = 0xFFFFFFFFu;
  __syncthreads();

  // bitonic sort lessList[M] ascending by (key, idx)
  for (int ksz = 2; ksz <= M; ksz <<= 1) {
    for (int j = ksz >> 1; j > 0; j >>= 1) {
      if (t < M) {
        int ixj = t ^ j;
        if (ixj > t) {
          u64 a = lessList[t], bb = lessList[ixj];
          bool up = ((t & ksz) == 0);
          if (up ? (a > bb) : (a < bb)) { lessList[t] = bb; lessList[ixj] = a; }
        }
      }
      __syncthreads();
    }
  }
  // bitonic sort eqList[256] ascending by idx
  for (int ksz = 2; ksz <= 256; ksz <<= 1) {
    for (int j = ksz >> 1; j > 0; j >>= 1) {
      int ixj = t ^ j;
      if (ixj > t) {
        u32 a = eqList[t], bb = eqList[ixj];
        bool up = ((t & ksz) == 0);
        if (up ? (a > bb) : (a < bb)) { eqList[t] = bb; eqList[ixj] = a; }
      }
      __syncthreads();
    }
  }

  if (t < M) {
    int idx = (t < nl) ? (int)(lessList[t] & 0xFFFFFFFFu) : (int)eqList[t - nl];
    size_t src = ((size_t)b * N + idx) * 3;
    size_t dst = ((size_t)bk * M + t) * 3;
    neighbor[dst]     = x[src];
    neighbor[dst + 1] = x[src + 1];
    neighbor[dst + 2] = x[src + 2];
  }
}

__global__ void k_fps(const float* __restrict__ neighbor, const int* __restrict__ farthest0,
                      float* __restrict__ out) {
  __shared__ float px[M], py[M], pz[M];
  __shared__ float wv[2];
  __shared__ int wi[2];
  int bg = blockIdx.x;  // b*64 + g
  int b = bg >> 6, g = bg & 63;
  int t = threadIdx.x;  // 128 threads = M
  size_t src = ((size_t)bg * M + t) * 3;
  float mx = neighbor[src], my = neighbor[src + 1], mz = neighbor[src + 2];
  px[t] = mx; py[t] = my; pz[t] = mz;
  int far = farthest0[bg];
  float dist = 1e10f;
  __syncthreads();
  for (int s = 0; s < S; ++s) {
    // record current farthest (scan outputs OLD carry), then update
    if (t == far) {
      size_t dst = ((size_t)b * 4096 + g * 64 + s) * 3;
      out[dst] = mx; out[dst + 1] = my; out[dst + 2] = mz;
    }
    float cx = px[far], cy = py[far], cz = pz[far];
    float dx = __fsub_rn(mx, cx), dy = __fsub_rn(my, cy), dz = __fsub_rn(mz, cz);
    float d = sq3(dx, dy, dz);
    dist = fminf(dist, d);
    float v = dist;
    int i = t;
#pragma unroll
    for (int off = 1; off < 64; off <<= 1) {
      float ov = __shfl_xor(v, off);
      int oi = __shfl_xor(i, off);
      if (ov > v || (ov == v && oi < i)) { v = ov; i = oi; }
    }
    int wid = t >> 6;
    if ((t & 63) == 0) { wv[wid] = v; wi[wid] = i; }
    __syncthreads();
    float v0 = wv[0]; int i0 = wi[0];
    float v1 = wv[1]; int i1 = wi[1];
    far = (v1 > v0 || (v1 == v0 && i1 < i0)) ? i1 : i0;  // first-occurrence argmax
    __syncthreads();
  }
}

__global__ void k_copy_centers(const float* __restrict__ centers, float* __restrict__ out) {
  int i = blockIdx.x * blockDim.x + threadIdx.x;
  if (i < B * KC * 3) out[B * 4096 * 3 + i] = centers[i];
}

extern "C" void kernel_launch(void* const* d_in, const int* in_sizes, int n_in,
                              void* d_out, int out_size, void* d_ws, size_t ws_size,
                              hipStream_t stream) {
  const float* x = (const float*)d_in[0];
  const int* farthest0 = (const int*)d_in[1];
  float* out = (float*)d_out;

  char* w = (char*)d_ws;
  float* centers         = (float*)(w);                         // 6144 B
  int* totals            = (int*)(w + 8192);                    // 2048 B
  int* kBase             = (int*)(w + 16384);                   // 2048 B
  unsigned char* cl      = (unsigned char*)(w + 24576);         // 524288 B
  int* hist              = (int*)(w + 24576 + 524288);          // 524288 B
  int* chunkOff          = (int*)(w + 24576 + 2 * 524288);      // 524288 B
  float* sortedPts       = (float*)(w + 24576 + 3 * 524288);    // 6291456 B
  float* neighbor        = (float*)(w + 24576 + 3 * 524288 + 6291456); // 786432 B
  // total ws use ≈ 8.7 MB

  k_init_centers<<<6, 256, 0, stream>>>(x, centers);
  for (int it = 0; it < NITER; ++it) {
    k_assign<<<B * NCHUNK, 256, 0, stream>>>(x, centers, cl, hist);
    k_scan_chunks<<<2, 256, 0, stream>>>(hist, chunkOff, totals);
    k_batch_prefix<<<1, 64, 0, stream>>>(totals, kBase);
    k_scatter<<<B * NCHUNK, 256, 0, stream>>>(x, cl, chunkOff, kBase, sortedPts);
    k_sum_divide<<<B * KC, 256, 0, stream>>>(sortedPts, kBase, totals, centers);
  }
  k_query_topk<<<B * KC, 256, 0, stream>>>(x, centers, neighbor);
  k_fps<<<B * KC, M, 0, stream>>>(neighbor, farthest0, out);
  k_copy_centers<<<6, 256, 0, stream>>>(centers, out);
}

// Round 6
// 1424.290 us; speedup vs baseline: 1.0059x; 1.0059x over previous
//
#include <hip/hip_runtime.h>
#include <stdint.h>

#pragma clang fp contract(off)

#define B 8
#define N 65536
#define KC 64        // clusters
#define M 128        // neighbors per center (NPOINT/K*2)
#define S 64         // fps samples per group (NPOINT/K)
#define NITER 10
#define CHUNK 256
#define NCHUNK (N / CHUNK)   // 256
#define SUMCHUNK 2048        // points staged in LDS per pass in k_sum_divide

using u32 = unsigned int;
using u64 = unsigned long long;

// ---- exact fp32 helpers (no FMA contraction, fixed association) ----
__device__ __forceinline__ float sq3(float a, float b, float c) {
  return __fadd_rn(__fadd_rn(__fmul_rn(a, a), __fmul_rn(b, b)), __fmul_rn(c, c));
}
__device__ __forceinline__ float dot3(float x0, float x1, float x2,
                                      float c0, float c1, float c2) {
  return __fadd_rn(__fadd_rn(__fmul_rn(x0, c0), __fmul_rn(x1, c1)), __fmul_rn(x2, c2));
}
__device__ __forceinline__ float distf(float s2, float d2, float dt) {
  // (s2 + d2) - 2*dot   — matches reference op order
  return __fsub_rn(__fadd_rn(s2, d2), __fmul_rn(2.0f, dt));
}
// monotone float->uint key (total order preserving)
__device__ __forceinline__ u32 fkey(float f) {
  u32 u = __float_as_uint(f);
  return (u & 0x80000000u) ? ~u : (u | 0x80000000u);
}

// ---- kernels ----

__global__ void k_init_centers(const float* __restrict__ x, float* __restrict__ centers) {
  int i = blockIdx.x * blockDim.x + threadIdx.x;
  if (i >= B * KC * 3) return;
  int b = i / (KC * 3);
  int r = i % (KC * 3);
  centers[i] = x[(size_t)b * N * 3 + r];   // c = x[:, :K, :]
}

__global__ void k_assign(const float* __restrict__ x, const float* __restrict__ centers,
                         unsigned char* __restrict__ cl, int* __restrict__ hist) {
  __shared__ float cx[KC], cy[KC], cz[KC], d2s[KC];
  __shared__ int lh[KC];
  int b = blockIdx.x >> 8;
  int chunk = blockIdx.x & 255;
  int t = threadIdx.x;
  if (t < KC) {
    float a0 = centers[(b * KC + t) * 3 + 0];
    float a1 = centers[(b * KC + t) * 3 + 1];
    float a2 = centers[(b * KC + t) * 3 + 2];
    cx[t] = a0; cy[t] = a1; cz[t] = a2;
    d2s[t] = sq3(a0, a1, a2);
    lh[t] = 0;
  }
  __syncthreads();
  int n = chunk * CHUNK + t;
  size_t xb = ((size_t)b * N + n) * 3;
  float x0 = x[xb], x1 = x[xb + 1], x2 = x[xb + 2];
  float s2 = sq3(x0, x1, x2);
  float best = __int_as_float(0x7f800000);  // +inf
  int bi = 0;
  for (int k = 0; k < KC; ++k) {
    float dt = dot3(x0, x1, x2, cx[k], cy[k], cz[k]);
    float d = distf(s2, d2s[k], dt);
    if (d < best) { best = d; bi = k; }     // first-min tie-break == argmin
  }
  cl[(size_t)b * N + n] = (unsigned char)bi;
  atomicAdd(&lh[bi], 1);
  __syncthreads();
  if (t < KC) hist[((b * NCHUNK) + chunk) * KC + t] = lh[t];
}

__global__ void k_scan_chunks(const int* __restrict__ hist, int* __restrict__ chunkOff,
                              int* __restrict__ totals) {
  int gt = blockIdx.x * blockDim.x + threadIdx.x;
  if (gt >= B * KC) return;
  int b = gt >> 6, k = gt & 63;
  int run = 0;
  for (int c = 0; c < NCHUNK; ++c) {
    int idx = ((b * NCHUNK) + c) * KC + k;
    chunkOff[idx] = run;
    run += hist[idx];
  }
  totals[gt] = run;
}

__global__ void k_batch_prefix(const int* __restrict__ totals, int* __restrict__ kBase) {
  int b = threadIdx.x;
  if (b >= B) return;
  int base = 0;
  for (int k = 0; k < KC; ++k) { kBase[b * KC + k] = base; base += totals[b * KC + k]; }
}

// stable counting-sort scatter: writes point coords grouped by cluster, in
// increasing original index order within each cluster (matches np.add.at order)
__global__ void k_scatter(const float* __restrict__ x, const unsigned char* __restrict__ cl,
                          const int* __restrict__ chunkOff, const int* __restrict__ kBase,
                          float* __restrict__ sortedPts) {
  __shared__ unsigned char lcl[CHUNK];
  int b = blockIdx.x >> 8, chunk = blockIdx.x & 255, t = threadIdx.x;
  int n = chunk * CHUNK + t;
  lcl[t] = cl[(size_t)b * N + n];
  __syncthreads();
  int k = lcl[t];
  int rank = 0;
  for (int j = 0; j < t; ++j) rank += (lcl[j] == k);
  int pos = kBase[b * KC + k] + chunkOff[((b * NCHUNK) + chunk) * KC + k] + rank;
  size_t src = ((size_t)b * N + n) * 3;
  size_t dst = ((size_t)b * N + pos) * 3;
  sortedPts[dst]     = x[src];
  sortedPts[dst + 1] = x[src + 1];
  sortedPts[dst + 2] = x[src + 2];
}

// one block per (b,k): cooperative LDS staging, lane 0 does the strictly
// sequential fp32 sum in original index order (bit-identical to np.add.at)
__global__ void k_sum_divide(const float* __restrict__ sortedPts,
                             const int* __restrict__ kBase, const int* __restrict__ totals,
                             float* __restrict__ centers) {
  __shared__ float buf[3 * SUMCHUNK];
  int gt = blockIdx.x;         // b*KC + k
  int b = gt >> 6;
  int t = threadIdx.x;
  int off = kBase[gt], cnt = totals[gt];
  const float* sp = sortedPts + ((size_t)b * N + off) * 3;
  float sx = 0.f, sy = 0.f, sz = 0.f;
  for (int base = 0; base < cnt; base += SUMCHUNK) {
    int m = min(SUMCHUNK, cnt - base);
    int nf = m * 3;
    for (int i = t; i < nf; i += 256) buf[i] = sp[(size_t)base * 3 + i];
    __syncthreads();
    if (t == 0) {
#pragma unroll 4
      for (int i = 0; i < m; ++i) {
        sx = __fadd_rn(sx, buf[3 * i]);
        sy = __fadd_rn(sy, buf[3 * i + 1]);
        sz = __fadd_rn(sz, buf[3 * i + 2]);
      }
    }
    __syncthreads();
  }
  if (t == 0) {
    float fc = (float)cnt;
    centers[gt * 3 + 0] = __fdiv_rn(sx, fc);
    centers[gt * 3 + 1] = __fdiv_rn(sy, fc);
    centers[gt * 3 + 2] = __fdiv_rn(sz, fc);
  }
}

// exact top-M (smallest distance, lower-index tiebreak) per (b,center)
// via 4-round byte radix-select on monotone keys + exact (key,idx) sort.
__global__ void k_query_topk(const float* __restrict__ x, const float* __restrict__ centers,
                             float* __restrict__ neighbor) {
  __shared__ u32 hist[256];
  __shared__ u64 lessList[M];
  __shared__ u32 eqList[256];
  __shared__ u32 sPrefix;
  __shared__ int sNeed;
  __shared__ int cntLess, cntEq;
  __shared__ float sc0, sc1, sc2, sd2;

  int bk = blockIdx.x;      // b*KC + k
  int b = bk >> 6;
  int t = threadIdx.x;
  if (t == 0) {
    float c0 = centers[bk * 3], c1 = centers[bk * 3 + 1], c2 = centers[bk * 3 + 2];
    sc0 = c0; sc1 = c1; sc2 = c2; sd2 = sq3(c0, c1, c2);
    cntLess = 0; cntEq = 0;
  }
  __syncthreads();
  float c0 = sc0, c1 = sc1, c2 = sc2, d2 = sd2;
  const float* xb = x + (size_t)b * N * 3;

  u32 prefix = 0;
  int need = M;
  for (int r = 3; r >= 0; --r) {
    for (int i = t; i < 256; i += 256) hist[i] = 0;
    __syncthreads();
    int sh = r * 8;
    for (int n = t; n < N; n += 256) {
      float x0 = xb[n * 3], x1 = xb[n * 3 + 1], x2 = xb[n * 3 + 2];
      float d = distf(sq3(x0, x1, x2), d2, dot3(x0, x1, x2, c0, c1, c2));
      u32 key = fkey(d);
      bool ok = (r == 3) || ((key >> (sh + 8)) == (prefix >> (sh + 8)));
      if (ok) atomicAdd(&hist[(key >> sh) & 255u], 1u);
    }
    __syncthreads();
    if (t == 0) {
      int cum = 0;
      for (int bin = 0; bin < 256; ++bin) {
        int c = (int)hist[bin];
        if (cum + c >= need) { sPrefix = prefix | ((u32)bin << sh); sNeed = need - cum; break; }
        cum += c;
      }
    }
    __syncthreads();
    prefix = sPrefix; need = sNeed;
    __syncthreads();
  }
  u32 K128 = prefix;   // exact key of the M-th smallest distance

  for (int n = t; n < N; n += 256) {
    float x0 = xb[n * 3], x1 = xb[n * 3 + 1], x2 = xb[n * 3 + 2];
    float d = distf(sq3(x0, x1, x2), d2, dot3(x0, x1, x2, c0, c1, c2));
    u32 key = fkey(d);
    if (key < K128) {
      int p = atomicAdd(&cntLess, 1);
      if (p < M) lessList[p] = ((u64)key << 32) | (u32)n;   // p < M guaranteed
    } else if (key == K128) {
      int p = atomicAdd(&cntEq, 1);
      if (p < 256) eqList[p] = (u32)n;
    }
  }
  __syncthreads();
  int nl = cntLess;   // < M by construction
  int ne = cntEq;
  for (int i = t; i < M; i += 256) if (i >= nl) lessList[i] = ~0ull;
  for (int i = t; i < 256; i += 256) if (i >= ne) eqList[i] = 0xFFFFFFFFu;
  __syncthreads();

  // bitonic sort lessList[M] ascending by (key, idx)
  for (int ksz = 2; ksz <= M; ksz <<= 1) {
    for (int j = ksz >> 1; j > 0; j >>= 1) {
      if (t < M) {
        int ixj = t ^ j;
        if (ixj > t) {
          u64 a = lessList[t], bb = lessList[ixj];
          bool up = ((t & ksz) == 0);
          if (up ? (a > bb) : (a < bb)) { lessList[t] = bb; lessList[ixj] = a; }
        }
      }
      __syncthreads();
    }
  }
  // bitonic sort eqList[256] ascending by idx
  for (int ksz = 2; ksz <= 256; ksz <<= 1) {
    for (int j = ksz >> 1; j > 0; j >>= 1) {
      int ixj = t ^ j;
      if (ixj > t) {
        u32 a = eqList[t], bb = eqList[ixj];
        bool up = ((t & ksz) == 0);
        if (up ? (a > bb) : (a < bb)) { eqList[t] = bb; eqList[ixj] = a; }
      }
      __syncthreads();
    }
  }

  if (t < M) {
    int idx = (t < nl) ? (int)(lessList[t] & 0xFFFFFFFFu) : (int)eqList[t - nl];
    size_t src = ((size_t)b * N + idx) * 3;
    size_t dst = ((size_t)bk * M + t) * 3;
    neighbor[dst]     = x[src];
    neighbor[dst + 1] = x[src + 1];
    neighbor[dst + 2] = x[src + 2];
  }
}

__global__ void k_fps(const float* __restrict__ neighbor, const int* __restrict__ farthest0,
                      float* __restrict__ out) {
  __shared__ float px[M], py[M], pz[M];
  __shared__ float wv[2];
  __shared__ int wi[2];
  int bg = blockIdx.x;  // b*64 + g
  int b = bg >> 6, g = bg & 63;
  int t = threadIdx.x;  // 128 threads = M
  size_t src = ((size_t)bg * M + t) * 3;
  float mx = neighbor[src], my = neighbor[src + 1], mz = neighbor[src + 2];
  px[t] = mx; py[t] = my; pz[t] = mz;
  int far = farthest0[bg];
  float dist = 1e10f;
  __syncthreads();
  for (int s = 0; s < S; ++s) {
    // record current farthest (scan outputs OLD carry), then update
    if (t == far) {
      size_t dst = ((size_t)b * 4096 + g * 64 + s) * 3;
      out[dst] = mx; out[dst + 1] = my; out[dst + 2] = mz;
    }
    float cx = px[far], cy = py[far], cz = pz[far];
    float dx = __fsub_rn(mx, cx), dy = __fsub_rn(my, cy), dz = __fsub_rn(mz, cz);
    float d = sq3(dx, dy, dz);
    dist = fminf(dist, d);
    float v = dist;
    int i = t;
#pragma unroll
    for (int off = 1; off < 64; off <<= 1) {
      float ov = __shfl_xor(v, off);
      int oi = __shfl_xor(i, off);
      if (ov > v || (ov == v && oi < i)) { v = ov; i = oi; }
    }
    int wid = t >> 6;
    if ((t & 63) == 0) { wv[wid] = v; wi[wid] = i; }
    __syncthreads();
    float v0 = wv[0]; int i0 = wi[0];
    float v1 = wv[1]; int i1 = wi[1];
    far = (v1 > v0 || (v1 == v0 && i1 < i0)) ? i1 : i0;  // first-occurrence argmax
    __syncthreads();
  }
}

__global__ void k_copy_centers(const float* __restrict__ centers, float* __restrict__ out) {
  int i = blockIdx.x * blockDim.x + threadIdx.x;
  if (i < B * KC * 3) out[B * 4096 * 3 + i] = centers[i];
}

extern "C" void kernel_launch(void* const* d_in, const int* in_sizes, int n_in,
                              void* d_out, int out_size, void* d_ws, size_t ws_size,
                              hipStream_t stream) {
  const float* x = (const float*)d_in[0];
  const int* farthest0 = (const int*)d_in[1];
  float* out = (float*)d_out;

  char* w = (char*)d_ws;
  float* centers         = (float*)(w);                         // 6144 B
  int* totals            = (int*)(w + 8192);                    // 2048 B
  int* kBase             = (int*)(w + 16384);                   // 2048 B
  unsigned char* cl      = (unsigned char*)(w + 24576);         // 524288 B
  int* hist              = (int*)(w + 24576 + 524288);          // 524288 B
  int* chunkOff          = (int*)(w + 24576 + 2 * 524288);      // 524288 B
  float* sortedPts       = (float*)(w + 24576 + 3 * 524288);    // 6291456 B
  float* neighbor        = (float*)(w + 24576 + 3 * 524288 + 6291456); // 786432 B
  // total ws use ≈ 8.7 MB

  k_init_centers<<<6, 256, 0, stream>>>(x, centers);
  for (int it = 0; it < NITER; ++it) {
    k_assign<<<B * NCHUNK, 256, 0, stream>>>(x, centers, cl, hist);
    k_scan_chunks<<<2, 256, 0, stream>>>(hist, chunkOff, totals);
    k_batch_prefix<<<1, 64, 0, stream>>>(totals, kBase);
    k_scatter<<<B * NCHUNK, 256, 0, stream>>>(x, cl, chunkOff, kBase, sortedPts);
    k_sum_divide<<<B * KC, 256, 0, stream>>>(sortedPts, kBase, totals, centers);
  }
  k_query_topk<<<B * KC, 256, 0, stream>>>(x, centers, neighbor);
  k_fps<<<B * KC, M, 0, stream>>>(neighbor, farthest0, out);
  k_copy_centers<<<6, 256, 0, stream>>>(centers, out);
}

// Round 7
// 1017.839 us; speedup vs baseline: 1.4076x; 1.3993x over previous
//
#include <hip/hip_runtime.h>
#include <stdint.h>

#pragma clang fp contract(off)

#define B 8
#define N 65536
#define KC 64        // clusters
#define M 128        // neighbors per center (NPOINT/K*2)
#define S 64         // fps samples per group (NPOINT/K)
#define NITER 10
#define CHUNK 256
#define NCHUNK (N / CHUNK)   // 256
#define SUMCHUNK 2048        // points staged in LDS per pass in k_sum_divide
#define TOPK_T 1024          // threads per top-k block
#define CAP 2048             // max same-byte candidates for the in-LDS fast path

using u32 = unsigned int;
using u64 = unsigned long long;

// ---- exact fp32 helpers (no FMA contraction, fixed association) ----
__device__ __forceinline__ float sq3(float a, float b, float c) {
  return __fadd_rn(__fadd_rn(__fmul_rn(a, a), __fmul_rn(b, b)), __fmul_rn(c, c));
}
__device__ __forceinline__ float dot3(float x0, float x1, float x2,
                                      float c0, float c1, float c2) {
  return __fadd_rn(__fadd_rn(__fmul_rn(x0, c0), __fmul_rn(x1, c1)), __fmul_rn(x2, c2));
}
__device__ __forceinline__ float distf(float s2, float d2, float dt) {
  // (s2 + d2) - 2*dot   — matches reference op order
  return __fsub_rn(__fadd_rn(s2, d2), __fmul_rn(2.0f, dt));
}
// monotone float->uint key (total order preserving)
__device__ __forceinline__ u32 fkey(float f) {
  u32 u = __float_as_uint(f);
  return (u & 0x80000000u) ? ~u : (u | 0x80000000u);
}

// ---- kernels ----

__global__ void k_init_centers(const float* __restrict__ x, float* __restrict__ centers) {
  int i = blockIdx.x * blockDim.x + threadIdx.x;
  if (i >= B * KC * 3) return;
  int b = i / (KC * 3);
  int r = i % (KC * 3);
  centers[i] = x[(size_t)b * N * 3 + r];   // c = x[:, :K, :]
}

__global__ void k_assign(const float* __restrict__ x, const float* __restrict__ centers,
                         unsigned char* __restrict__ cl, int* __restrict__ hist) {
  __shared__ float cx[KC], cy[KC], cz[KC], d2s[KC];
  __shared__ int lh[KC];
  int b = blockIdx.x >> 8;
  int chunk = blockIdx.x & 255;
  int t = threadIdx.x;
  if (t < KC) {
    float a0 = centers[(b * KC + t) * 3 + 0];
    float a1 = centers[(b * KC + t) * 3 + 1];
    float a2 = centers[(b * KC + t) * 3 + 2];
    cx[t] = a0; cy[t] = a1; cz[t] = a2;
    d2s[t] = sq3(a0, a1, a2);
    lh[t] = 0;
  }
  __syncthreads();
  int n = chunk * CHUNK + t;
  size_t xb = ((size_t)b * N + n) * 3;
  float x0 = x[xb], x1 = x[xb + 1], x2 = x[xb + 2];
  float s2 = sq3(x0, x1, x2);
  float best = __int_as_float(0x7f800000);  // +inf
  int bi = 0;
  for (int k = 0; k < KC; ++k) {
    float dt = dot3(x0, x1, x2, cx[k], cy[k], cz[k]);
    float d = distf(s2, d2s[k], dt);
    if (d < best) { best = d; bi = k; }     // first-min tie-break == argmin
  }
  cl[(size_t)b * N + n] = (unsigned char)bi;
  atomicAdd(&lh[bi], 1);
  __syncthreads();
  if (t < KC) hist[((b * NCHUNK) + chunk) * KC + t] = lh[t];
}

// one block per (b,k): Hillis-Steele exclusive scan over the 256 chunk counts
// (integer adds — association-free, exactness unaffected)
__global__ void k_scan_chunks(const int* __restrict__ hist, int* __restrict__ chunkOff,
                              int* __restrict__ totals) {
  __shared__ int sv[NCHUNK];
  int gt = blockIdx.x;   // b*KC + k
  int b = gt >> 6, k = gt & 63;
  int t = threadIdx.x;   // NCHUNK = 256 threads
  int idx = ((b * NCHUNK) + t) * KC + k;
  int own = hist[idx];
  sv[t] = own;
  __syncthreads();
  for (int off = 1; off < NCHUNK; off <<= 1) {
    int add = (t >= off) ? sv[t - off] : 0;
    __syncthreads();
    sv[t] += add;
    __syncthreads();
  }
  chunkOff[idx] = sv[t] - own;   // exclusive
  if (t == NCHUNK - 1) totals[gt] = sv[t];
}

__global__ void k_batch_prefix(const int* __restrict__ totals, int* __restrict__ kBase) {
  int b = threadIdx.x;
  if (b >= B) return;
  int base = 0;
  for (int k = 0; k < KC; ++k) { kBase[b * KC + k] = base; base += totals[b * KC + k]; }
}

// stable counting-sort scatter: writes point coords grouped by cluster, in
// increasing original index order within each cluster (matches np.add.at order)
__global__ void k_scatter(const float* __restrict__ x, const unsigned char* __restrict__ cl,
                          const int* __restrict__ chunkOff, const int* __restrict__ kBase,
                          float* __restrict__ sortedPts) {
  __shared__ unsigned char lcl[CHUNK];
  int b = blockIdx.x >> 8, chunk = blockIdx.x & 255, t = threadIdx.x;
  int n = chunk * CHUNK + t;
  lcl[t] = cl[(size_t)b * N + n];
  __syncthreads();
  int k = lcl[t];
  int rank = 0;
  for (int j = 0; j < t; ++j) rank += (lcl[j] == k);   // broadcast LDS reads
  int pos = kBase[b * KC + k] + chunkOff[((b * NCHUNK) + chunk) * KC + k] + rank;
  size_t src = ((size_t)b * N + n) * 3;
  size_t dst = ((size_t)b * N + pos) * 3;
  sortedPts[dst]     = x[src];
  sortedPts[dst + 1] = x[src + 1];
  sortedPts[dst + 2] = x[src + 2];
}

// one block per (b,k): cooperative LDS staging, lane 0 does the strictly
// sequential fp32 sum in original index order (bit-identical to np.add.at)
__global__ void k_sum_divide(const float* __restrict__ sortedPts,
                             const int* __restrict__ kBase, const int* __restrict__ totals,
                             float* __restrict__ centers) {
  __shared__ float buf[3 * SUMCHUNK];
  int gt = blockIdx.x;         // b*KC + k
  int b = gt >> 6;
  int t = threadIdx.x;
  int off = kBase[gt], cnt = totals[gt];
  const float* sp = sortedPts + ((size_t)b * N + off) * 3;
  float sx = 0.f, sy = 0.f, sz = 0.f;
  for (int base = 0; base < cnt; base += SUMCHUNK) {
    int m = min(SUMCHUNK, cnt - base);
    int nf = m * 3;
    for (int i = t; i < nf; i += 256) buf[i] = sp[(size_t)base * 3 + i];
    __syncthreads();
    if (t == 0) {
#pragma unroll 4
      for (int i = 0; i < m; ++i) {
        sx = __fadd_rn(sx, buf[3 * i]);
        sy = __fadd_rn(sy, buf[3 * i + 1]);
        sz = __fadd_rn(sz, buf[3 * i + 2]);
      }
    }
    __syncthreads();
  }
  if (t == 0) {
    float fc = (float)cnt;
    centers[gt * 3 + 0] = __fdiv_rn(sx, fc);
    centers[gt * 3 + 1] = __fdiv_rn(sy, fc);
    centers[gt * 3 + 2] = __fdiv_rn(sz, fc);
  }
}

// exact top-M (smallest distance, lower-index tiebreak) per (b,center).
// Fast path: 1 histogram scan + 1 collection scan, then exact in-LDS bitonic
// refinement of the same-top-byte candidates. Fallback (candidates > CAP):
// full byte-radix refinement as before. Both paths bit-identical to reference.
__global__ __launch_bounds__(TOPK_T)
void k_query_topk(const float* __restrict__ x, const float* __restrict__ centers,
                  float* __restrict__ neighbor) {
  __shared__ u32 hist[256];
  __shared__ u64 lessList[M];
  __shared__ u64 candList[CAP];
  __shared__ u32 eqList[256];
  __shared__ u32 sPrefix;
  __shared__ int sNeed, sCntBin;
  __shared__ int cntLess, cntEq;
  __shared__ float sc0, sc1, sc2, sd2;

  int bk = blockIdx.x;      // b*KC + k
  int b = bk >> 6;
  int t = threadIdx.x;
  if (t == 0) {
    float c0 = centers[bk * 3], c1 = centers[bk * 3 + 1], c2 = centers[bk * 3 + 2];
    sc0 = c0; sc1 = c1; sc2 = c2; sd2 = sq3(c0, c1, c2);
    cntLess = 0; cntEq = 0;
  }
  for (int i = t; i < 256; i += TOPK_T) hist[i] = 0;
  __syncthreads();
  float c0 = sc0, c1 = sc1, c2 = sc2, d2 = sd2;
  const float* xb = x + (size_t)b * N * 3;

  // ---- scan 1: 8-bit histogram of all N keys ----
  for (int n = t; n < N; n += TOPK_T) {
    float x0 = xb[n * 3], x1 = xb[n * 3 + 1], x2 = xb[n * 3 + 2];
    float d = distf(sq3(x0, x1, x2), d2, dot3(x0, x1, x2, c0, c1, c2));
    atomicAdd(&hist[fkey(d) >> 24], 1u);
  }
  __syncthreads();
  if (t == 0) {
    int cum = 0;
    for (int bin = 0; bin < 256; ++bin) {
      int c = (int)hist[bin];
      if (cum + c >= M) { sPrefix = (u32)bin; sNeed = M - cum; sCntBin = c; break; }
      cum += c;
    }
  }
  __syncthreads();
  u32 selByte = sPrefix;
  int needEq = sNeed;      // how many winners come from the selByte bin
  int cntBin = sCntBin;    // how many candidates share that top byte

  if (cntBin <= CAP) {
    // ---- fast path: scan 2 collects, LDS finishes ----
    for (int n = t; n < N; n += TOPK_T) {
      float x0 = xb[n * 3], x1 = xb[n * 3 + 1], x2 = xb[n * 3 + 2];
      float d = distf(sq3(x0, x1, x2), d2, dot3(x0, x1, x2, c0, c1, c2));
      u32 key = fkey(d);
      u32 pb = key >> 24;
      if (pb < selByte) {
        int p = atomicAdd(&cntLess, 1);            // < M guaranteed by histogram
        lessList[p] = ((u64)key << 32) | (u32)n;
      } else if (pb == selByte) {
        int p = atomicAdd(&cntEq, 1);              // <= CAP guaranteed
        candList[p] = ((u64)key << 32) | (u32)n;
      }
    }
    __syncthreads();
    int nl = cntLess;        // == M - needEq
    int ne = cntEq;          // == cntBin
    int P = 1; while (P < ne) P <<= 1;
    for (int i = t; i < M; i += TOPK_T) if (i >= nl) lessList[i] = ~0ull;
    for (int i = t; i < P; i += TOPK_T) if (i >= ne) candList[i] = ~0ull;
    __syncthreads();
    // bitonic sort lessList[M] ascending by (key, idx)
    for (int ksz = 2; ksz <= M; ksz <<= 1) {
      for (int j = ksz >> 1; j > 0; j >>= 1) {
        for (int idx = t; idx < M; idx += TOPK_T) {
          int ixj = idx ^ j;
          if (ixj > idx) {
            u64 a = lessList[idx], bb = lessList[ixj];
            bool up = ((idx & ksz) == 0);
            if (up ? (a > bb) : (a < bb)) { lessList[idx] = bb; lessList[ixj] = a; }
          }
        }
        __syncthreads();
      }
    }
    // bitonic sort candList[P] ascending by (key, idx)
    for (int ksz = 2; ksz <= P; ksz <<= 1) {
      for (int j = ksz >> 1; j > 0; j >>= 1) {
        for (int idx = t; idx < P; idx += TOPK_T) {
          int ixj = idx ^ j;
          if (ixj > idx) {
            u64 a = candList[idx], bb = candList[ixj];
            bool up = ((idx & ksz) == 0);
            if (up ? (a > bb) : (a < bb)) { candList[idx] = bb; candList[ixj] = a; }
          }
        }
        __syncthreads();
      }
    }
    if (t < M) {
      u64 e = (t < nl) ? lessList[t] : candList[t - nl];
      int idx = (int)(e & 0xFFFFFFFFu);
      size_t src = ((size_t)b * N + idx) * 3;
      size_t dst = ((size_t)bk * M + t) * 3;
      neighbor[dst]     = x[src];
      neighbor[dst + 1] = x[src + 1];
      neighbor[dst + 2] = x[src + 2];
    }
    return;
  }

  // ---- fallback: full byte-radix refinement (rounds 2..0) ----
  u32 prefix = selByte << 24;
  int need = needEq;
  for (int r = 2; r >= 0; --r) {
    for (int i = t; i < 256; i += TOPK_T) hist[i] = 0;
    __syncthreads();
    int sh = r * 8;
    for (int n = t; n < N; n += TOPK_T) {
      float x0 = xb[n * 3], x1 = xb[n * 3 + 1], x2 = xb[n * 3 + 2];
      float d = distf(sq3(x0, x1, x2), d2, dot3(x0, x1, x2, c0, c1, c2));
      u32 key = fkey(d);
      if ((key >> (sh + 8)) == (prefix >> (sh + 8)))
        atomicAdd(&hist[(key >> sh) & 255u], 1u);
    }
    __syncthreads();
    if (t == 0) {
      int cum = 0;
      for (int bin = 0; bin < 256; ++bin) {
        int c = (int)hist[bin];
        if (cum + c >= need) { sPrefix = prefix | ((u32)bin << sh); sNeed = need - cum; break; }
        cum += c;
      }
    }
    __syncthreads();
    prefix = sPrefix; need = sNeed;
    __syncthreads();
  }
  u32 K128 = prefix;   // exact key of the M-th smallest distance

  if (t == 0) { cntLess = 0; cntEq = 0; }
  __syncthreads();
  for (int n = t; n < N; n += TOPK_T) {
    float x0 = xb[n * 3], x1 = xb[n * 3 + 1], x2 = xb[n * 3 + 2];
    float d = distf(sq3(x0, x1, x2), d2, dot3(x0, x1, x2, c0, c1, c2));
    u32 key = fkey(d);
    if (key < K128) {
      int p = atomicAdd(&cntLess, 1);
      if (p < M) lessList[p] = ((u64)key << 32) | (u32)n;
    } else if (key == K128) {
      int p = atomicAdd(&cntEq, 1);
      if (p < 256) eqList[p] = (u32)n;
    }
  }
  __syncthreads();
  int nl = cntLess;
  int ne = cntEq;
  for (int i = t; i < M; i += TOPK_T) if (i >= nl) lessList[i] = ~0ull;
  for (int i = t; i < 256; i += TOPK_T) if (i >= ne) eqList[i] = 0xFFFFFFFFu;
  __syncthreads();

  for (int ksz = 2; ksz <= M; ksz <<= 1) {
    for (int j = ksz >> 1; j > 0; j >>= 1) {
      for (int idx = t; idx < M; idx += TOPK_T) {
        int ixj = idx ^ j;
        if (ixj > idx) {
          u64 a = lessList[idx], bb = lessList[ixj];
          bool up = ((idx & ksz) == 0);
          if (up ? (a > bb) : (a < bb)) { lessList[idx] = bb; lessList[ixj] = a; }
        }
      }
      __syncthreads();
    }
  }
  for (int ksz = 2; ksz <= 256; ksz <<= 1) {
    for (int j = ksz >> 1; j > 0; j >>= 1) {
      for (int idx = t; idx < 256; idx += TOPK_T) {
        int ixj = idx ^ j;
        if (ixj > idx) {
          u32 a = eqList[idx], bb = eqList[ixj];
          bool up = ((idx & ksz) == 0);
          if (up ? (a > bb) : (a < bb)) { eqList[idx] = bb; eqList[ixj] = a; }
        }
      }
      __syncthreads();
    }
  }

  if (t < M) {
    int idx = (t < nl) ? (int)(lessList[t] & 0xFFFFFFFFu) : (int)eqList[t - nl];
    size_t src = ((size_t)b * N + idx) * 3;
    size_t dst = ((size_t)bk * M + t) * 3;
    neighbor[dst]     = x[src];
    neighbor[dst + 1] = x[src + 1];
    neighbor[dst + 2] = x[src + 2];
  }
}

__global__ void k_fps(const float* __restrict__ neighbor, const int* __restrict__ farthest0,
                      float* __restrict__ out) {
  __shared__ float px[M], py[M], pz[M];
  __shared__ float wv[2];
  __shared__ int wi[2];
  int bg = blockIdx.x;  // b*64 + g
  int b = bg >> 6, g = bg & 63;
  int t = threadIdx.x;  // 128 threads = M
  size_t src = ((size_t)bg * M + t) * 3;
  float mx = neighbor[src], my = neighbor[src + 1], mz = neighbor[src + 2];
  px[t] = mx; py[t] = my; pz[t] = mz;
  int far = farthest0[bg];
  float dist = 1e10f;
  __syncthreads();
  for (int s = 0; s < S; ++s) {
    // record current farthest (scan outputs OLD carry), then update
    if (t == far) {
      size_t dst = ((size_t)b * 4096 + g * 64 + s) * 3;
      out[dst] = mx; out[dst + 1] = my; out[dst + 2] = mz;
    }
    float cx = px[far], cy = py[far], cz = pz[far];
    float dx = __fsub_rn(mx, cx), dy = __fsub_rn(my, cy), dz = __fsub_rn(mz, cz);
    float d = sq3(dx, dy, dz);
    dist = fminf(dist, d);
    float v = dist;
    int i = t;
#pragma unroll
    for (int off = 1; off < 64; off <<= 1) {
      float ov = __shfl_xor(v, off);
      int oi = __shfl_xor(i, off);
      if (ov > v || (ov == v && oi < i)) { v = ov; i = oi; }
    }
    int wid = t >> 6;
    if ((t & 63) == 0) { wv[wid] = v; wi[wid] = i; }
    __syncthreads();
    float v0 = wv[0]; int i0 = wi[0];
    float v1 = wv[1]; int i1 = wi[1];
    far = (v1 > v0 || (v1 == v0 && i1 < i0)) ? i1 : i0;  // first-occurrence argmax
    __syncthreads();
  }
}

__global__ void k_copy_centers(const float* __restrict__ centers, float* __restrict__ out) {
  int i = blockIdx.x * blockDim.x + threadIdx.x;
  if (i < B * KC * 3) out[B * 4096 * 3 + i] = centers[i];
}

extern "C" void kernel_launch(void* const* d_in, const int* in_sizes, int n_in,
                              void* d_out, int out_size, void* d_ws, size_t ws_size,
                              hipStream_t stream) {
  const float* x = (const float*)d_in[0];
  const int* farthest0 = (const int*)d_in[1];
  float* out = (float*)d_out;

  char* w = (char*)d_ws;
  float* centers         = (float*)(w);                         // 6144 B
  int* totals            = (int*)(w + 8192);                    // 2048 B
  int* kBase             = (int*)(w + 16384);                   // 2048 B
  unsigned char* cl      = (unsigned char*)(w + 24576);         // 524288 B
  int* hist              = (int*)(w + 24576 + 524288);          // 524288 B
  int* chunkOff          = (int*)(w + 24576 + 2 * 524288);      // 524288 B
  float* sortedPts       = (float*)(w + 24576 + 3 * 524288);    // 6291456 B
  float* neighbor        = (float*)(w + 24576 + 3 * 524288 + 6291456); // 786432 B
  // total ws use ≈ 8.7 MB

  k_init_centers<<<6, 256, 0, stream>>>(x, centers);
  for (int it = 0; it < NITER; ++it) {
    k_assign<<<B * NCHUNK, 256, 0, stream>>>(x, centers, cl, hist);
    k_scan_chunks<<<B * KC, NCHUNK, 0, stream>>>(hist, chunkOff, totals);
    k_batch_prefix<<<1, 64, 0, stream>>>(totals, kBase);
    k_scatter<<<B * NCHUNK, 256, 0, stream>>>(x, cl, chunkOff, kBase, sortedPts);
    k_sum_divide<<<B * KC, 256, 0, stream>>>(sortedPts, kBase, totals, centers);
  }
  k_query_topk<<<B * KC, TOPK_T, 0, stream>>>(x, centers, neighbor);
  k_fps<<<B * KC, M, 0, stream>>>(neighbor, farthest0, out);
  k_copy_centers<<<6, 256, 0, stream>>>(centers, out);
}

// Round 8
// 960.752 us; speedup vs baseline: 1.4913x; 1.0594x over previous
//
#include <hip/hip_runtime.h>
#include <stdint.h>

#pragma clang fp contract(off)

#define B 8
#define N 65536
#define KC 64        // clusters
#define M 128        // neighbors per center (NPOINT/K*2)
#define S 64         // fps samples per group (NPOINT/K)
#define NITER 10
#define CHUNK 256
#define NCHUNK (N / CHUNK)   // 256
#define SUMCHUNK 2048        // points staged in LDS per pass in k_sum_divide
#define TOPK_T 1024          // threads per top-k block
#define NWAVES (TOPK_T / 64) // 16
#define HPAD 257             // padded per-wave histogram stride (bank-decorrelated)
#define CAP 2048             // max same-byte candidates for the in-LDS fast path

using u32 = unsigned int;
using u64 = unsigned long long;

// ---- exact fp32 helpers (no FMA contraction, fixed association) ----
__device__ __forceinline__ float sq3(float a, float b, float c) {
  return __fadd_rn(__fadd_rn(__fmul_rn(a, a), __fmul_rn(b, b)), __fmul_rn(c, c));
}
__device__ __forceinline__ float dot3(float x0, float x1, float x2,
                                      float c0, float c1, float c2) {
  return __fadd_rn(__fadd_rn(__fmul_rn(x0, c0), __fmul_rn(x1, c1)), __fmul_rn(x2, c2));
}
__device__ __forceinline__ float distf(float s2, float d2, float dt) {
  // (s2 + d2) - 2*dot   — matches reference op order
  return __fsub_rn(__fadd_rn(s2, d2), __fmul_rn(2.0f, dt));
}
// monotone float->uint key (total order preserving)
__device__ __forceinline__ u32 fkey(float f) {
  u32 u = __float_as_uint(f);
  return (u & 0x80000000u) ? ~u : (u | 0x80000000u);
}

// ---- kernels ----

__global__ void k_init_centers(const float* __restrict__ x, float* __restrict__ centers) {
  int i = blockIdx.x * blockDim.x + threadIdx.x;
  if (i >= B * KC * 3) return;
  int b = i / (KC * 3);
  int r = i % (KC * 3);
  centers[i] = x[(size_t)b * N * 3 + r];   // c = x[:, :K, :]
}

__global__ void k_assign(const float* __restrict__ x, const float* __restrict__ centers,
                         unsigned char* __restrict__ cl, int* __restrict__ hist) {
  __shared__ float cx[KC], cy[KC], cz[KC], d2s[KC];
  __shared__ int lh[KC];
  int b = blockIdx.x >> 8;
  int chunk = blockIdx.x & 255;
  int t = threadIdx.x;
  if (t < KC) {
    float a0 = centers[(b * KC + t) * 3 + 0];
    float a1 = centers[(b * KC + t) * 3 + 1];
    float a2 = centers[(b * KC + t) * 3 + 2];
    cx[t] = a0; cy[t] = a1; cz[t] = a2;
    d2s[t] = sq3(a0, a1, a2);
    lh[t] = 0;
  }
  __syncthreads();
  int n = chunk * CHUNK + t;
  size_t xb = ((size_t)b * N + n) * 3;
  float x0 = x[xb], x1 = x[xb + 1], x2 = x[xb + 2];
  float s2 = sq3(x0, x1, x2);
  float best = __int_as_float(0x7f800000);  // +inf
  int bi = 0;
  for (int k = 0; k < KC; ++k) {
    float dt = dot3(x0, x1, x2, cx[k], cy[k], cz[k]);
    float d = distf(s2, d2s[k], dt);
    if (d < best) { best = d; bi = k; }     // first-min tie-break == argmin
  }
  cl[(size_t)b * N + n] = (unsigned char)bi;
  atomicAdd(&lh[bi], 1);
  __syncthreads();
  if (t < KC) hist[((b * NCHUNK) + chunk) * KC + t] = lh[t];
}

// one block per (b,k): Hillis-Steele exclusive scan over the 256 chunk counts
// (integer adds — association-free, exactness unaffected)
__global__ void k_scan_chunks(const int* __restrict__ hist, int* __restrict__ chunkOff,
                              int* __restrict__ totals) {
  __shared__ int sv[NCHUNK];
  int gt = blockIdx.x;   // b*KC + k
  int b = gt >> 6, k = gt & 63;
  int t = threadIdx.x;   // NCHUNK = 256 threads
  int idx = ((b * NCHUNK) + t) * KC + k;
  int own = hist[idx];
  sv[t] = own;
  __syncthreads();
  for (int off = 1; off < NCHUNK; off <<= 1) {
    int add = (t >= off) ? sv[t - off] : 0;
    __syncthreads();
    sv[t] += add;
    __syncthreads();
  }
  chunkOff[idx] = sv[t] - own;   // exclusive
  if (t == NCHUNK - 1) totals[gt] = sv[t];
}

// stable counting-sort scatter: writes point coords grouped by cluster, in
// increasing original index order within each cluster (matches np.add.at order).
// kBase (exclusive prefix of totals over k) computed in-kernel by wave 0.
__global__ void k_scatter(const float* __restrict__ x, const unsigned char* __restrict__ cl,
                          const int* __restrict__ chunkOff, const int* __restrict__ totals,
                          float* __restrict__ sortedPts) {
  __shared__ unsigned char lcl[CHUNK];
  __shared__ int kb[KC];
  int b = blockIdx.x >> 8, chunk = blockIdx.x & 255, t = threadIdx.x;
  if (t < KC) {
    int v = totals[b * KC + t];
    int incl = v;
#pragma unroll
    for (int o = 1; o < 64; o <<= 1) {
      int u = __shfl_up(incl, o);
      if ((t & 63) >= o) incl += u;
    }
    kb[t] = incl - v;   // exclusive prefix
  }
  int n = chunk * CHUNK + t;
  lcl[t] = cl[(size_t)b * N + n];
  __syncthreads();
  int k = lcl[t];
  int rank = 0;
  for (int j = 0; j < t; ++j) rank += (lcl[j] == k);   // broadcast LDS reads
  int pos = kb[k] + chunkOff[((b * NCHUNK) + chunk) * KC + k] + rank;
  size_t src = ((size_t)b * N + n) * 3;
  size_t dst = ((size_t)b * N + pos) * 3;
  sortedPts[dst]     = x[src];
  sortedPts[dst + 1] = x[src + 1];
  sortedPts[dst + 2] = x[src + 2];
}

// one block per (b,k): cooperative LDS staging, lane 0 does the strictly
// sequential fp32 sum in original index order (bit-identical to np.add.at)
__global__ void k_sum_divide(const float* __restrict__ sortedPts,
                             const int* __restrict__ totals,
                             float* __restrict__ centers) {
  __shared__ float buf[3 * SUMCHUNK];
  __shared__ int kb[KC];
  int gt = blockIdx.x;         // b*KC + k
  int b = gt >> 6, k = gt & 63;
  int t = threadIdx.x;
  if (t < KC) {
    int v = totals[b * KC + t];
    int incl = v;
#pragma unroll
    for (int o = 1; o < 64; o <<= 1) {
      int u = __shfl_up(incl, o);
      if ((t & 63) >= o) incl += u;
    }
    kb[t] = incl - v;
  }
  __syncthreads();
  int off = kb[k];
  int cnt = totals[gt];
  const float* sp = sortedPts + ((size_t)b * N + off) * 3;
  float sx = 0.f, sy = 0.f, sz = 0.f;
  for (int base = 0; base < cnt; base += SUMCHUNK) {
    int m = min(SUMCHUNK, cnt - base);
    int nf = m * 3;
    for (int i = t; i < nf; i += 256) buf[i] = sp[(size_t)base * 3 + i];
    __syncthreads();
    if (t == 0) {
#pragma unroll 4
      for (int i = 0; i < m; ++i) {
        sx = __fadd_rn(sx, buf[3 * i]);
        sy = __fadd_rn(sy, buf[3 * i + 1]);
        sz = __fadd_rn(sz, buf[3 * i + 2]);
      }
    }
    __syncthreads();
  }
  if (t == 0) {
    float fc = (float)cnt;
    centers[gt * 3 + 0] = __fdiv_rn(sx, fc);
    centers[gt * 3 + 1] = __fdiv_rn(sy, fc);
    centers[gt * 3 + 2] = __fdiv_rn(sz, fc);
  }
}

// exact top-M (smallest distance, lower-index tiebreak) per (b,center).
// Scan 1: ballot-dedup per-wave histogram (no atomics, no bank conflicts).
// Scan 2: collect winners + same-top-byte candidates, exact in-LDS bitonic
// refinement. Fallback (candidates > CAP): full byte-radix (bit-identical).
__global__ __launch_bounds__(TOPK_T)
void k_query_topk(const float* __restrict__ x, const float* __restrict__ centers,
                  float* __restrict__ neighbor) {
  __shared__ u32 whist[NWAVES * HPAD];
  __shared__ u32 hist[256];
  __shared__ u64 lessList[M];
  __shared__ u64 candList[CAP];
  __shared__ u32 eqList[256];
  __shared__ u32 sPrefix;
  __shared__ int sNeed, sCntBin;
  __shared__ int cntLess, cntEq;
  __shared__ float sc0, sc1, sc2, sd2;

  int g = blockIdx.x;
  int bk = ((g & 7) << 6) | (g >> 3);   // batch = g & 7 -> XCD-affine (512 blocks, 8 XCDs)
  int b = bk >> 6;
  int t = threadIdx.x;
  int lane = t & 63, wid = t >> 6;
  if (t == 0) {
    float c0 = centers[bk * 3], c1 = centers[bk * 3 + 1], c2 = centers[bk * 3 + 2];
    sc0 = c0; sc1 = c1; sc2 = c2; sd2 = sq3(c0, c1, c2);
    cntLess = 0; cntEq = 0;
  }
  for (int i = t; i < NWAVES * HPAD; i += TOPK_T) whist[i] = 0;
  __syncthreads();
  float c0 = sc0, c1 = sc1, c2 = sc2, d2 = sd2;
  const float* xb = x + (size_t)b * N * 3;
  const float2* xb2 = (const float2*)xb;

  // ---- scan 1: per-wave ballot-dedup histogram of all N key top-bytes ----
  // full-wave convergent loop: N/2 = 32768 pairs, TOPK_T strides -> 32 exact iters
  for (int p = t; p < N / 2; p += TOPK_T) {
    float2 A = xb2[3 * p], Bv = xb2[3 * p + 1], C = xb2[3 * p + 2];
    float d0 = distf(sq3(A.x, A.y, Bv.x), d2, dot3(A.x, A.y, Bv.x, c0, c1, c2));
    float d1 = distf(sq3(Bv.y, C.x, C.y), d2, dot3(Bv.y, C.x, C.y, c0, c1, c2));
    u32 b0 = fkey(d0) >> 24;
    u32 b1 = fkey(d1) >> 24;
    u64 rem = ~0ull;
    while (rem) {
      int leader = __ffsll((unsigned long long)rem) - 1;
      u32 lb = __shfl((int)b0, leader);
      u64 eq = __ballot(b0 == lb);
      if (lane == leader) whist[wid * HPAD + lb] += (u32)__popcll(eq);
      rem &= ~eq;
    }
    rem = ~0ull;
    while (rem) {
      int leader = __ffsll((unsigned long long)rem) - 1;
      u32 lb = __shfl((int)b1, leader);
      u64 eq = __ballot(b1 == lb);
      if (lane == leader) whist[wid * HPAD + lb] += (u32)__popcll(eq);
      rem &= ~eq;
    }
  }
  __syncthreads();
  // reduce 16 per-wave histograms -> hist[256]
  if (t < 256) {
    u32 s = 0;
#pragma unroll
    for (int w = 0; w < NWAVES; ++w) s += whist[w * HPAD + t];
    hist[t] = s;
  }
  __syncthreads();
  if (t == 0) {
    int cum = 0;
    for (int bin = 0; bin < 256; ++bin) {
      int c = (int)hist[bin];
      if (cum + c >= M) { sPrefix = (u32)bin; sNeed = M - cum; sCntBin = c; break; }
      cum += c;
    }
  }
  __syncthreads();
  u32 selByte = sPrefix;
  int needEq = sNeed;      // winners from the selByte bin
  int cntBin = sCntBin;    // candidates sharing that top byte

  if (cntBin <= CAP) {
    // ---- fast path: scan 2 collects, LDS finishes ----
    for (int p = t; p < N / 2; p += TOPK_T) {
      float2 A = xb2[3 * p], Bv = xb2[3 * p + 1], C = xb2[3 * p + 2];
      float d0 = distf(sq3(A.x, A.y, Bv.x), d2, dot3(A.x, A.y, Bv.x, c0, c1, c2));
      float d1 = distf(sq3(Bv.y, C.x, C.y), d2, dot3(Bv.y, C.x, C.y, c0, c1, c2));
      u32 key0 = fkey(d0), key1 = fkey(d1);
      u32 pb0 = key0 >> 24, pb1 = key1 >> 24;
      if (pb0 < selByte) {
        int q = atomicAdd(&cntLess, 1);
        lessList[q] = ((u64)key0 << 32) | (u32)(2 * p);
      } else if (pb0 == selByte) {
        int q = atomicAdd(&cntEq, 1);
        candList[q] = ((u64)key0 << 32) | (u32)(2 * p);
      }
      if (pb1 < selByte) {
        int q = atomicAdd(&cntLess, 1);
        lessList[q] = ((u64)key1 << 32) | (u32)(2 * p + 1);
      } else if (pb1 == selByte) {
        int q = atomicAdd(&cntEq, 1);
        candList[q] = ((u64)key1 << 32) | (u32)(2 * p + 1);
      }
    }
    __syncthreads();
    int nl = cntLess;        // == M - needEq  (< M)
    int ne = cntEq;          // == cntBin      (<= CAP)
    int P = 1; while (P < ne) P <<= 1;
    for (int i = t; i < M; i += TOPK_T) if (i >= nl) lessList[i] = ~0ull;
    for (int i = t; i < P; i += TOPK_T) if (i >= ne) candList[i] = ~0ull;
    __syncthreads();
    // bitonic sort lessList[M] ascending by (key, idx)
    for (int ksz = 2; ksz <= M; ksz <<= 1) {
      for (int j = ksz >> 1; j > 0; j >>= 1) {
        for (int idx = t; idx < M; idx += TOPK_T) {
          int ixj = idx ^ j;
          if (ixj > idx) {
            u64 a = lessList[idx], bb = lessList[ixj];
            bool up = ((idx & ksz) == 0);
            if (up ? (a > bb) : (a < bb)) { lessList[idx] = bb; lessList[ixj] = a; }
          }
        }
        __syncthreads();
      }
    }
    // bitonic sort candList[P] ascending by (key, idx)
    for (int ksz = 2; ksz <= P; ksz <<= 1) {
      for (int j = ksz >> 1; j > 0; j >>= 1) {
        for (int idx = t; idx < P; idx += TOPK_T) {
          int ixj = idx ^ j;
          if (ixj > idx) {
            u64 a = candList[idx], bb = candList[ixj];
            bool up = ((idx & ksz) == 0);
            if (up ? (a > bb) : (a < bb)) { candList[idx] = bb; candList[ixj] = a; }
          }
        }
        __syncthreads();
      }
    }
    if (t < M) {
      u64 e = (t < nl) ? lessList[t] : candList[t - nl];
      int idx = (int)(e & 0xFFFFFFFFu);
      size_t src = ((size_t)b * N + idx) * 3;
      size_t dst = ((size_t)bk * M + t) * 3;
      neighbor[dst]     = x[src];
      neighbor[dst + 1] = x[src + 1];
      neighbor[dst + 2] = x[src + 2];
    }
    return;
  }

  // ---- fallback: full byte-radix refinement (rounds 2..0) ----
  u32 prefix = selByte << 24;
  int need = needEq;
  for (int r = 2; r >= 0; --r) {
    for (int i = t; i < 256; i += TOPK_T) hist[i] = 0;
    __syncthreads();
    int sh = r * 8;
    for (int n = t; n < N; n += TOPK_T) {
      float x0 = xb[n * 3], x1 = xb[n * 3 + 1], x2 = xb[n * 3 + 2];
      float d = distf(sq3(x0, x1, x2), d2, dot3(x0, x1, x2, c0, c1, c2));
      u32 key = fkey(d);
      if ((key >> (sh + 8)) == (prefix >> (sh + 8)))
        atomicAdd(&hist[(key >> sh) & 255u], 1u);
    }
    __syncthreads();
    if (t == 0) {
      int cum = 0;
      for (int bin = 0; bin < 256; ++bin) {
        int c = (int)hist[bin];
        if (cum + c >= need) { sPrefix = prefix | ((u32)bin << sh); sNeed = need - cum; break; }
        cum += c;
      }
    }
    __syncthreads();
    prefix = sPrefix; need = sNeed;
    __syncthreads();
  }
  u32 K128 = prefix;   // exact key of the M-th smallest distance

  if (t == 0) { cntLess = 0; cntEq = 0; }
  __syncthreads();
  for (int n = t; n < N; n += TOPK_T) {
    float x0 = xb[n * 3], x1 = xb[n * 3 + 1], x2 = xb[n * 3 + 2];
    float d = distf(sq3(x0, x1, x2), d2, dot3(x0, x1, x2, c0, c1, c2));
    u32 key = fkey(d);
    if (key < K128) {
      int p = atomicAdd(&cntLess, 1);
      if (p < M) lessList[p] = ((u64)key << 32) | (u32)n;
    } else if (key == K128) {
      int p = atomicAdd(&cntEq, 1);
      if (p < 256) eqList[p] = (u32)n;
    }
  }
  __syncthreads();
  int nl = cntLess;
  int ne = cntEq;
  for (int i = t; i < M; i += TOPK_T) if (i >= nl) lessList[i] = ~0ull;
  for (int i = t; i < 256; i += TOPK_T) if (i >= ne) eqList[i] = 0xFFFFFFFFu;
  __syncthreads();

  for (int ksz = 2; ksz <= M; ksz <<= 1) {
    for (int j = ksz >> 1; j > 0; j >>= 1) {
      for (int idx = t; idx < M; idx += TOPK_T) {
        int ixj = idx ^ j;
        if (ixj > idx) {
          u64 a = lessList[idx], bb = lessList[ixj];
          bool up = ((idx & ksz) == 0);
          if (up ? (a > bb) : (a < bb)) { lessList[idx] = bb; lessList[ixj] = a; }
        }
      }
      __syncthreads();
    }
  }
  for (int ksz = 2; ksz <= 256; ksz <<= 1) {
    for (int j = ksz >> 1; j > 0; j >>= 1) {
      for (int idx = t; idx < 256; idx += TOPK_T) {
        int ixj = idx ^ j;
        if (ixj > idx) {
          u32 a = eqList[idx], bb = eqList[ixj];
          bool up = ((idx & ksz) == 0);
          if (up ? (a > bb) : (a < bb)) { eqList[idx] = bb; eqList[ixj] = a; }
        }
      }
      __syncthreads();
    }
  }

  if (t < M) {
    int idx = (t < nl) ? (int)(lessList[t] & 0xFFFFFFFFu) : (int)eqList[t - nl];
    size_t src = ((size_t)b * N + idx) * 3;
    size_t dst = ((size_t)bk * M + t) * 3;
    neighbor[dst]     = x[src];
    neighbor[dst + 1] = x[src + 1];
    neighbor[dst + 2] = x[src + 2];
  }
}

__global__ void k_fps(const float* __restrict__ neighbor, const int* __restrict__ farthest0,
                      const float* __restrict__ centers, float* __restrict__ out) {
  __shared__ float px[M], py[M], pz[M];
  __shared__ float wv[2];
  __shared__ int wi[2];
  int bg = blockIdx.x;  // b*64 + g
  int b = bg >> 6, g = bg & 63;
  int t = threadIdx.x;  // 128 threads = M
  // fused centers copy (blocks 0..11 handle 1536 floats)
  {
    int i = bg * 128 + t;
    if (i < B * KC * 3) out[B * 4096 * 3 + i] = centers[i];
  }
  size_t src = ((size_t)bg * M + t) * 3;
  float mx = neighbor[src], my = neighbor[src + 1], mz = neighbor[src + 2];
  px[t] = mx; py[t] = my; pz[t] = mz;
  int far = farthest0[bg];
  float dist = 1e10f;
  __syncthreads();
  for (int s = 0; s < S; ++s) {
    // record current farthest (scan outputs OLD carry), then update
    if (t == far) {
      size_t dst = ((size_t)b * 4096 + g * 64 + s) * 3;
      out[dst] = mx; out[dst + 1] = my; out[dst + 2] = mz;
    }
    float cx = px[far], cy = py[far], cz = pz[far];
    float dx = __fsub_rn(mx, cx), dy = __fsub_rn(my, cy), dz = __fsub_rn(mz, cz);
    float d = sq3(dx, dy, dz);
    dist = fminf(dist, d);
    float v = dist;
    int i = t;
#pragma unroll
    for (int off = 1; off < 64; off <<= 1) {
      float ov = __shfl_xor(v, off);
      int oi = __shfl_xor(i, off);
      if (ov > v || (ov == v && oi < i)) { v = ov; i = oi; }
    }
    int wid = t >> 6;
    if ((t & 63) == 0) { wv[wid] = v; wi[wid] = i; }
    __syncthreads();
    float v0 = wv[0]; int i0 = wi[0];
    float v1 = wv[1]; int i1 = wi[1];
    far = (v1 > v0 || (v1 == v0 && i1 < i0)) ? i1 : i0;  // first-occurrence argmax
    __syncthreads();
  }
}

extern "C" void kernel_launch(void* const* d_in, const int* in_sizes, int n_in,
                              void* d_out, int out_size, void* d_ws, size_t ws_size,
                              hipStream_t stream) {
  const float* x = (const float*)d_in[0];
  const int* farthest0 = (const int*)d_in[1];
  float* out = (float*)d_out;

  char* w = (char*)d_ws;
  float* centers         = (float*)(w);                         // 6144 B
  int* totals            = (int*)(w + 8192);                    // 2048 B
  unsigned char* cl      = (unsigned char*)(w + 24576);         // 524288 B
  int* hist              = (int*)(w + 24576 + 524288);          // 524288 B
  int* chunkOff          = (int*)(w + 24576 + 2 * 524288);      // 524288 B
  float* sortedPts       = (float*)(w + 24576 + 3 * 524288);    // 6291456 B
  float* neighbor        = (float*)(w + 24576 + 3 * 524288 + 6291456); // 786432 B
  // total ws use ≈ 8.7 MB

  k_init_centers<<<6, 256, 0, stream>>>(x, centers);
  for (int it = 0; it < NITER; ++it) {
    k_assign<<<B * NCHUNK, 256, 0, stream>>>(x, centers, cl, hist);
    k_scan_chunks<<<B * KC, NCHUNK, 0, stream>>>(hist, chunkOff, totals);
    k_scatter<<<B * NCHUNK, 256, 0, stream>>>(x, cl, chunkOff, totals, sortedPts);
    k_sum_divide<<<B * KC, 256, 0, stream>>>(sortedPts, totals, centers);
  }
  k_query_topk<<<B * KC, TOPK_T, 0, stream>>>(x, centers, neighbor);
  k_fps<<<B * KC, M, 0, stream>>>(neighbor, farthest0, centers, out);
}

// Round 9
// 560.785 us; speedup vs baseline: 2.5549x; 1.7132x over previous
//
#include <hip/hip_runtime.h>
#include <stdint.h>

#pragma clang fp contract(off)

#define B 8
#define N 65536
#define KC 64        // clusters
#define M 128        // neighbors per center (NPOINT/K*2)
#define S 64         // fps samples per group (NPOINT/K)
#define NITER 10
#define TOPK_T 1024          // threads per top-k block
#define NWAVES (TOPK_T / 64) // 16
#define HPAD 257             // padded per-wave histogram stride
#define CAP 2048             // max same-byte candidates for the in-LDS fast path
#define UPD_T 1024           // threads per cluster-update block
#define RANGE 16384          // points per range chunk in cluster update
#define NRANGE (N / RANGE)   // 4
#define PPT (RANGE / UPD_T)  // 16 points per thread
#define GBATCH 2048          // members gathered per sub-batch

using u32 = unsigned int;
using u64 = unsigned long long;

// ---- exact fp32 helpers (no FMA contraction, fixed association) ----
__device__ __forceinline__ float sq3(float a, float b, float c) {
  return __fadd_rn(__fadd_rn(__fmul_rn(a, a), __fmul_rn(b, b)), __fmul_rn(c, c));
}
__device__ __forceinline__ float dot3(float x0, float x1, float x2,
                                      float c0, float c1, float c2) {
  return __fadd_rn(__fadd_rn(__fmul_rn(x0, c0), __fmul_rn(x1, c1)), __fmul_rn(x2, c2));
}
__device__ __forceinline__ float distf(float s2, float d2, float dt) {
  // (s2 + d2) - 2*dot   — matches reference op order
  return __fsub_rn(__fadd_rn(s2, d2), __fmul_rn(2.0f, dt));
}
// monotone float->uint key (total order preserving)
__device__ __forceinline__ u32 fkey(float f) {
  u32 u = __float_as_uint(f);
  return (u & 0x80000000u) ? ~u : (u | 0x80000000u);
}

// ---- kernels ----

__global__ void k_init_centers(const float* __restrict__ x, float* __restrict__ centers) {
  int i = blockIdx.x * blockDim.x + threadIdx.x;
  if (i >= B * KC * 3) return;
  int b = i / (KC * 3);
  int r = i % (KC * 3);
  centers[i] = x[(size_t)b * N * 3 + r];   // c = x[:, :K, :]
}

// one-time |x|^2 precompute (x is constant across the whole pipeline)
__global__ void k_s2(const float* __restrict__ x, float* __restrict__ s2) {
  int i = blockIdx.x * blockDim.x + threadIdx.x;   // pair index, B*N/2 total
  const float2* x2 = (const float2*)x;
  float2 A = x2[3 * i], Bv = x2[3 * i + 1], C = x2[3 * i + 2];
  float2 o;
  o.x = sq3(A.x, A.y, Bv.x);
  o.y = sq3(Bv.y, C.x, C.y);
  ((float2*)s2)[i] = o;
}

// 2 points per thread, packed ushort cl store
__global__ void k_assign(const float* __restrict__ x, const float* __restrict__ centers,
                         unsigned char* __restrict__ cl) {
  __shared__ float4 cs[KC];
  int b = blockIdx.x >> 7;          // 128 chunks per batch
  int chunk = blockIdx.x & 127;
  int t = threadIdx.x;
  if (t < KC) {
    float a0 = centers[(b * KC + t) * 3 + 0];
    float a1 = centers[(b * KC + t) * 3 + 1];
    float a2 = centers[(b * KC + t) * 3 + 2];
    cs[t] = make_float4(a0, a1, a2, sq3(a0, a1, a2));
  }
  __syncthreads();
  int pr = chunk * 256 + t;         // pair index within batch (points 2pr, 2pr+1)
  const float2* xb2 = (const float2*)(x + (size_t)b * N * 3);
  float2 A = xb2[3 * pr], Bv = xb2[3 * pr + 1], C = xb2[3 * pr + 2];
  float s20 = sq3(A.x, A.y, Bv.x);
  float s21 = sq3(Bv.y, C.x, C.y);
  float best0 = __int_as_float(0x7f800000), best1 = best0;
  int bi0 = 0, bi1 = 0;
  for (int k = 0; k < KC; ++k) {
    float4 cc = cs[k];
    float d0 = distf(s20, cc.w, dot3(A.x, A.y, Bv.x, cc.x, cc.y, cc.z));
    float d1 = distf(s21, cc.w, dot3(Bv.y, C.x, C.y, cc.x, cc.y, cc.z));
    if (d0 < best0) { best0 = d0; bi0 = k; }   // first-min == argmin
    if (d1 < best1) { best1 = d1; bi1 = k; }
  }
  *(unsigned short*)(cl + (size_t)b * N + 2 * pr) =
      (unsigned short)(bi0 | (bi1 << 8));
}

// one block per (b,k): find own members from cl (stable, index order),
// gather coords to LDS, lanes 0/1/2 run the three sequential fp32 chains in
// lockstep — bit-identical to np.add.at's per-cluster sequential sum.
__global__ __launch_bounds__(UPD_T)
void k_cluster_update(const float* __restrict__ x, const unsigned char* __restrict__ cl,
                      float* __restrict__ centers) {
  __shared__ unsigned short midx[RANGE];          // 32 KB
  __shared__ float bcoord[3][GBATCH + 1];         // ~24 KB, padded stride
  __shared__ int woff[NWAVES];
  __shared__ int sCnt;
  int g = blockIdx.x;
  int bk = ((g & 7) << 6) | (g >> 3);             // XCD-affine: batch = g & 7
  int b = bk >> 6, k = bk & 63;
  int t = threadIdx.x, lane = t & 63, wid = t >> 6;
  const unsigned char* clb = cl + (size_t)b * N;
  const float* xb = x + (size_t)b * N * 3;
  float acc = 0.f;      // lanes 0/1/2 of wave 0 carry x/y/z sums
  int cntAll = 0;

  for (int r = 0; r < NRANGE; ++r) {
    // 1. count matches in my contiguous 16-point segment
    const uint4* cp = (const uint4*)(clb + r * RANGE);
    uint4 v = cp[t];
    u32 wsv[4] = {v.x, v.y, v.z, v.w};
    int m = 0;
#pragma unroll
    for (int j = 0; j < PPT; ++j)
      m += (((wsv[j >> 2] >> ((j & 3) * 8)) & 255u) == (u32)k);
    // 2. block exclusive scan of per-thread counts
    int incl = m;
#pragma unroll
    for (int o = 1; o < 64; o <<= 1) {
      int u = __shfl_up(incl, o);
      if (lane >= o) incl += u;
    }
    if (lane == 63) woff[wid] = incl;
    __syncthreads();
    if (t == 0) {
      int run = 0;
      for (int w = 0; w < NWAVES; ++w) { int vv = woff[w]; woff[w] = run; run += vv; }
      sCnt = run;
    }
    __syncthreads();
    int off = woff[wid] + incl - m;
    int mcnt = sCnt;
    // 3. write member local indices in ascending order (stable)
    int base = t * PPT;
#pragma unroll
    for (int j = 0; j < PPT; ++j) {
      if (((wsv[j >> 2] >> ((j & 3) * 8)) & 255u) == (u32)k)
        midx[off++] = (unsigned short)(base + j);
    }
    __syncthreads();
    // 4. gather + lockstep serial sum, in batches
    for (int bo = 0; bo < mcnt; bo += GBATCH) {
      int bn = min(GBATCH, mcnt - bo);
      for (int i = t; i < bn; i += UPD_T) {
        int li = midx[bo + i];
        size_t src = ((size_t)(r * RANGE + li)) * 3;
        bcoord[0][i] = xb[src];
        bcoord[1][i] = xb[src + 1];
        bcoord[2][i] = xb[src + 2];
      }
      __syncthreads();
      if (wid == 0 && lane < 3) {
        const float* mb = &bcoord[lane][0];     // per-lane base, bank-decorrelated
        for (int i = 0; i < bn; ++i) acc = __fadd_rn(acc, mb[i]);
      }
      __syncthreads();
    }
    cntAll += mcnt;
    __syncthreads();
  }
  if (wid == 0 && lane < 3)
    centers[bk * 3 + lane] = __fdiv_rn(acc, (float)cntAll);
}

// exact top-M (smallest distance, lower-index tiebreak) per (b,center).
// Scan 1: bit-ballot dedup per-wave histogram (branch-free, no atomics).
// Scan 2: collect winners + same-top-byte candidates, exact in-LDS bitonic
// refinement. Fallback (candidates > CAP): full byte-radix (bit-identical).
__global__ __launch_bounds__(TOPK_T)
void k_query_topk(const float* __restrict__ x, const float* __restrict__ s2g,
                  const float* __restrict__ centers, float* __restrict__ neighbor) {
  __shared__ u32 whist[NWAVES * HPAD];
  __shared__ u32 hist[256];
  __shared__ u64 lessList[M];
  __shared__ u64 candList[CAP];
  __shared__ u32 eqList[256];
  __shared__ u32 sPrefix;
  __shared__ int sNeed, sCntBin;
  __shared__ int cntLess, cntEq;
  __shared__ float sc0, sc1, sc2, sd2;

  int g = blockIdx.x;
  int bk = ((g & 7) << 6) | (g >> 3);   // batch = g & 7 -> XCD-affine
  int b = bk >> 6;
  int t = threadIdx.x;
  int lane = t & 63, wid = t >> 6;
  if (t == 0) {
    float c0 = centers[bk * 3], c1 = centers[bk * 3 + 1], c2 = centers[bk * 3 + 2];
    sc0 = c0; sc1 = c1; sc2 = c2; sd2 = sq3(c0, c1, c2);
    cntLess = 0; cntEq = 0;
  }
  for (int i = t; i < NWAVES * HPAD; i += TOPK_T) whist[i] = 0;
  __syncthreads();
  float c0 = sc0, c1 = sc1, c2 = sc2, d2 = sd2;
  const float* xb = x + (size_t)b * N * 3;
  const float2* xb2 = (const float2*)xb;
  const float2* s2b2 = (const float2*)(s2g + (size_t)b * N);

  // ---- scan 1: bit-ballot dedup per-wave histogram of key top-bytes ----
  // full-wave convergent: N/2 = 32768 pairs / 1024 threads = 32 exact iters
  for (int p = t; p < N / 2; p += TOPK_T) {
    float2 A = xb2[3 * p], Bv = xb2[3 * p + 1], C = xb2[3 * p + 2];
    float2 s2p = s2b2[p];
    float d0 = distf(s2p.x, d2, dot3(A.x, A.y, Bv.x, c0, c1, c2));
    float d1 = distf(s2p.y, d2, dot3(Bv.y, C.x, C.y, c0, c1, c2));
    u32 b0 = fkey(d0) >> 24;
    u32 b1 = fkey(d1) >> 24;
    u64 lt = ((u64)1 << lane) - 1;
    u64 eq0 = ~0ull, eq1 = ~0ull;
#pragma unroll
    for (int i = 0; i < 8; ++i) {
      u64 m0 = __ballot((b0 >> i) & 1);
      u64 m1 = __ballot((b1 >> i) & 1);
      eq0 &= ((b0 >> i) & 1) ? m0 : ~m0;
      eq1 &= ((b1 >> i) & 1) ? m1 : ~m1;
    }
    if ((eq0 & lt) == 0) whist[wid * HPAD + b0] += (u32)__popcll(eq0);
    if ((eq1 & lt) == 0) whist[wid * HPAD + b1] += (u32)__popcll(eq1);
  }
  __syncthreads();
  // reduce 16 per-wave histograms -> hist[256]
  if (t < 256) {
    u32 s = 0;
#pragma unroll
    for (int w = 0; w < NWAVES; ++w) s += whist[w * HPAD + t];
    hist[t] = s;
  }
  __syncthreads();
  if (t == 0) {
    int cum = 0;
    for (int bin = 0; bin < 256; ++bin) {
      int c = (int)hist[bin];
      if (cum + c >= M) { sPrefix = (u32)bin; sNeed = M - cum; sCntBin = c; break; }
      cum += c;
    }
  }
  __syncthreads();
  u32 selByte = sPrefix;
  int needEq = sNeed;      // winners from the selByte bin
  int cntBin = sCntBin;    // candidates sharing that top byte

  if (cntBin <= CAP) {
    // ---- fast path: scan 2 collects, LDS finishes ----
    for (int p = t; p < N / 2; p += TOPK_T) {
      float2 A = xb2[3 * p], Bv = xb2[3 * p + 1], C = xb2[3 * p + 2];
      float2 s2p = s2b2[p];
      float d0 = distf(s2p.x, d2, dot3(A.x, A.y, Bv.x, c0, c1, c2));
      float d1 = distf(s2p.y, d2, dot3(Bv.y, C.x, C.y, c0, c1, c2));
      u32 key0 = fkey(d0), key1 = fkey(d1);
      u32 pb0 = key0 >> 24, pb1 = key1 >> 24;
      if (pb0 < selByte) {
        int q = atomicAdd(&cntLess, 1);
        lessList[q] = ((u64)key0 << 32) | (u32)(2 * p);
      } else if (pb0 == selByte) {
        int q = atomicAdd(&cntEq, 1);
        candList[q] = ((u64)key0 << 32) | (u32)(2 * p);
      }
      if (pb1 < selByte) {
        int q = atomicAdd(&cntLess, 1);
        lessList[q] = ((u64)key1 << 32) | (u32)(2 * p + 1);
      } else if (pb1 == selByte) {
        int q = atomicAdd(&cntEq, 1);
        candList[q] = ((u64)key1 << 32) | (u32)(2 * p + 1);
      }
    }
    __syncthreads();
    int nl = cntLess;        // == M - needEq  (< M)
    int ne = cntEq;          // == cntBin      (<= CAP)
    int P = 1; while (P < ne) P <<= 1;
    for (int i = t; i < M; i += TOPK_T) if (i >= nl) lessList[i] = ~0ull;
    for (int i = t; i < P; i += TOPK_T) if (i >= ne) candList[i] = ~0ull;
    __syncthreads();
    // bitonic sort lessList[M] ascending by (key, idx)
    for (int ksz = 2; ksz <= M; ksz <<= 1) {
      for (int j = ksz >> 1; j > 0; j >>= 1) {
        for (int idx = t; idx < M; idx += TOPK_T) {
          int ixj = idx ^ j;
          if (ixj > idx) {
            u64 a = lessList[idx], bb = lessList[ixj];
            bool up = ((idx & ksz) == 0);
            if (up ? (a > bb) : (a < bb)) { lessList[idx] = bb; lessList[ixj] = a; }
          }
        }
        __syncthreads();
      }
    }
    // bitonic sort candList[P] ascending by (key, idx)
    for (int ksz = 2; ksz <= P; ksz <<= 1) {
      for (int j = ksz >> 1; j > 0; j >>= 1) {
        for (int idx = t; idx < P; idx += TOPK_T) {
          int ixj = idx ^ j;
          if (ixj > idx) {
            u64 a = candList[idx], bb = candList[ixj];
            bool up = ((idx & ksz) == 0);
            if (up ? (a > bb) : (a < bb)) { candList[idx] = bb; candList[ixj] = a; }
          }
        }
        __syncthreads();
      }
    }
    if (t < M) {
      u64 e = (t < nl) ? lessList[t] : candList[t - nl];
      int idx = (int)(e & 0xFFFFFFFFu);
      size_t src = ((size_t)b * N + idx) * 3;
      size_t dst = ((size_t)bk * M + t) * 3;
      neighbor[dst]     = x[src];
      neighbor[dst + 1] = x[src + 1];
      neighbor[dst + 2] = x[src + 2];
    }
    return;
  }

  // ---- fallback: full byte-radix refinement (rounds 2..0) ----
  u32 prefix = selByte << 24;
  int need = needEq;
  for (int r = 2; r >= 0; --r) {
    for (int i = t; i < 256; i += TOPK_T) hist[i] = 0;
    __syncthreads();
    int sh = r * 8;
    for (int n = t; n < N; n += TOPK_T) {
      float x0 = xb[n * 3], x1 = xb[n * 3 + 1], x2 = xb[n * 3 + 2];
      float d = distf(sq3(x0, x1, x2), d2, dot3(x0, x1, x2, c0, c1, c2));
      u32 key = fkey(d);
      if ((key >> (sh + 8)) == (prefix >> (sh + 8)))
        atomicAdd(&hist[(key >> sh) & 255u], 1u);
    }
    __syncthreads();
    if (t == 0) {
      int cum = 0;
      for (int bin = 0; bin < 256; ++bin) {
        int c = (int)hist[bin];
        if (cum + c >= need) { sPrefix = prefix | ((u32)bin << sh); sNeed = need - cum; break; }
        cum += c;
      }
    }
    __syncthreads();
    prefix = sPrefix; need = sNeed;
    __syncthreads();
  }
  u32 K128 = prefix;   // exact key of the M-th smallest distance

  if (t == 0) { cntLess = 0; cntEq = 0; }
  __syncthreads();
  for (int n = t; n < N; n += TOPK_T) {
    float x0 = xb[n * 3], x1 = xb[n * 3 + 1], x2 = xb[n * 3 + 2];
    float d = distf(sq3(x0, x1, x2), d2, dot3(x0, x1, x2, c0, c1, c2));
    u32 key = fkey(d);
    if (key < K128) {
      int p = atomicAdd(&cntLess, 1);
      if (p < M) lessList[p] = ((u64)key << 32) | (u32)n;
    } else if (key == K128) {
      int p = atomicAdd(&cntEq, 1);
      if (p < 256) eqList[p] = (u32)n;
    }
  }
  __syncthreads();
  int nl = cntLess;
  int ne = cntEq;
  for (int i = t; i < M; i += TOPK_T) if (i >= nl) lessList[i] = ~0ull;
  for (int i = t; i < 256; i += TOPK_T) if (i >= ne) eqList[i] = 0xFFFFFFFFu;
  __syncthreads();

  for (int ksz = 2; ksz <= M; ksz <<= 1) {
    for (int j = ksz >> 1; j > 0; j >>= 1) {
      for (int idx = t; idx < M; idx += TOPK_T) {
        int ixj = idx ^ j;
        if (ixj > idx) {
          u64 a = lessList[idx], bb = lessList[ixj];
          bool up = ((idx & ksz) == 0);
          if (up ? (a > bb) : (a < bb)) { lessList[idx] = bb; lessList[ixj] = a; }
        }
      }
      __syncthreads();
    }
  }
  for (int ksz = 2; ksz <= 256; ksz <<= 1) {
    for (int j = ksz >> 1; j > 0; j >>= 1) {
      for (int idx = t; idx < 256; idx += TOPK_T) {
        int ixj = idx ^ j;
        if (ixj > idx) {
          u32 a = eqList[idx], bb = eqList[ixj];
          bool up = ((idx & ksz) == 0);
          if (up ? (a > bb) : (a < bb)) { eqList[idx] = bb; eqList[ixj] = a; }
        }
      }
      __syncthreads();
    }
  }

  if (t < M) {
    int idx = (t < nl) ? (int)(lessList[t] & 0xFFFFFFFFu) : (int)eqList[t - nl];
    size_t src = ((size_t)b * N + idx) * 3;
    size_t dst = ((size_t)bk * M + t) * 3;
    neighbor[dst]     = x[src];
    neighbor[dst + 1] = x[src + 1];
    neighbor[dst + 2] = x[src + 2];
  }
}

__global__ void k_fps(const float* __restrict__ neighbor, const int* __restrict__ farthest0,
                      const float* __restrict__ centers, float* __restrict__ out) {
  __shared__ float px[M], py[M], pz[M];
  __shared__ float wv[2];
  __shared__ int wi[2];
  int bg = blockIdx.x;  // b*64 + g
  int b = bg >> 6, g = bg & 63;
  int t = threadIdx.x;  // 128 threads = M
  // fused centers copy (blocks 0..11 handle 1536 floats)
  {
    int i = bg * 128 + t;
    if (i < B * KC * 3) out[B * 4096 * 3 + i] = centers[i];
  }
  size_t src = ((size_t)bg * M + t) * 3;
  float mx = neighbor[src], my = neighbor[src + 1], mz = neighbor[src + 2];
  px[t] = mx; py[t] = my; pz[t] = mz;
  int far = farthest0[bg];
  float dist = 1e10f;
  __syncthreads();
  for (int s = 0; s < S; ++s) {
    // record current farthest (scan outputs OLD carry), then update
    if (t == far) {
      size_t dst = ((size_t)b * 4096 + g * 64 + s) * 3;
      out[dst] = mx; out[dst + 1] = my; out[dst + 2] = mz;
    }
    float cx = px[far], cy = py[far], cz = pz[far];
    float dx = __fsub_rn(mx, cx), dy = __fsub_rn(my, cy), dz = __fsub_rn(mz, cz);
    float d = sq3(dx, dy, dz);
    dist = fminf(dist, d);
    float v = dist;
    int i = t;
#pragma unroll
    for (int off = 1; off < 64; off <<= 1) {
      float ov = __shfl_xor(v, off);
      int oi = __shfl_xor(i, off);
      if (ov > v || (ov == v && oi < i)) { v = ov; i = oi; }
    }
    int wid = t >> 6;
    if ((t & 63) == 0) { wv[wid] = v; wi[wid] = i; }
    __syncthreads();
    float v0 = wv[0]; int i0 = wi[0];
    float v1 = wv[1]; int i1 = wi[1];
    far = (v1 > v0 || (v1 == v0 && i1 < i0)) ? i1 : i0;  // first-occurrence argmax
    __syncthreads();
  }
}

extern "C" void kernel_launch(void* const* d_in, const int* in_sizes, int n_in,
                              void* d_out, int out_size, void* d_ws, size_t ws_size,
                              hipStream_t stream) {
  const float* x = (const float*)d_in[0];
  const int* farthest0 = (const int*)d_in[1];
  float* out = (float*)d_out;

  char* w = (char*)d_ws;
  float* centers         = (float*)(w);                       // 6144 B
  unsigned char* cl      = (unsigned char*)(w + 8192);        // 524288 B
  float* s2              = (float*)(w + 8192 + 524288);       // 2097152 B
  float* neighbor        = (float*)(w + 8192 + 524288 + 2097152); // 786432 B
  // total ws use ≈ 3.4 MB

  k_init_centers<<<6, 256, 0, stream>>>(x, centers);
  k_s2<<<B * N / 2 / 256, 256, 0, stream>>>(x, s2);
  for (int it = 0; it < NITER; ++it) {
    k_assign<<<B * 128, 256, 0, stream>>>(x, centers, cl);
    k_cluster_update<<<B * KC, UPD_T, 0, stream>>>(x, cl, centers);
  }
  k_query_topk<<<B * KC, TOPK_T, 0, stream>>>(x, s2, centers, neighbor);
  k_fps<<<B * KC, M, 0, stream>>>(neighbor, farthest0, centers, out);
}

// Round 10
// 552.443 us; speedup vs baseline: 2.5934x; 1.0151x over previous
//
#include <hip/hip_runtime.h>
#include <stdint.h>

#pragma clang fp contract(off)

#define B 8
#define N 65536
#define KC 64        // clusters
#define M 128        // neighbors per center (NPOINT/K*2)
#define S 64         // fps samples per group (NPOINT/K)
#define NITER 10
#define TOPK_T 1024          // threads per top-k block
#define NWAVES (TOPK_T / 64) // 16
#define HPAD 257             // padded per-wave histogram stride
#define SAMPLE 8192          // prefix sample size for threshold
#define SCAP 2048            // sample same-byte candidate cap (u32 keys)
#define CAP 2048             // full-scan candidate cap (u64 key|idx)
#define UPD_T 1024           // threads per cluster-update block
#define RANGE 16384          // points per range chunk in cluster update
#define NRANGE (N / RANGE)   // 4
#define PPT (RANGE / UPD_T)  // 16 points per thread
#define GBATCH 2048          // members gathered per sub-batch

using u32 = unsigned int;
using u64 = unsigned long long;

// ---- exact fp32 helpers (no FMA contraction, fixed association) ----
__device__ __forceinline__ float sq3(float a, float b, float c) {
  return __fadd_rn(__fadd_rn(__fmul_rn(a, a), __fmul_rn(b, b)), __fmul_rn(c, c));
}
__device__ __forceinline__ float dot3(float x0, float x1, float x2,
                                      float c0, float c1, float c2) {
  return __fadd_rn(__fadd_rn(__fmul_rn(x0, c0), __fmul_rn(x1, c1)), __fmul_rn(x2, c2));
}
__device__ __forceinline__ float distf(float s2, float d2, float dt) {
  // (s2 + d2) - 2*dot   — matches reference op order
  return __fsub_rn(__fadd_rn(s2, d2), __fmul_rn(2.0f, dt));
}
// monotone float->uint key (total order preserving)
__device__ __forceinline__ u32 fkey(float f) {
  u32 u = __float_as_uint(f);
  return (u & 0x80000000u) ? ~u : (u | 0x80000000u);
}

// ---- kernels ----

__global__ void k_init_centers(const float* __restrict__ x, float* __restrict__ centers) {
  int i = blockIdx.x * blockDim.x + threadIdx.x;
  if (i >= B * KC * 3) return;
  int b = i / (KC * 3);
  int r = i % (KC * 3);
  centers[i] = x[(size_t)b * N * 3 + r];   // c = x[:, :K, :]
}

// one-time |x|^2 precompute (x is constant across the whole pipeline)
__global__ void k_s2(const float* __restrict__ x, float* __restrict__ s2) {
  int i = blockIdx.x * blockDim.x + threadIdx.x;   // pair index, B*N/2 total
  const float2* x2 = (const float2*)x;
  float2 A = x2[3 * i], Bv = x2[3 * i + 1], C = x2[3 * i + 2];
  float2 o;
  o.x = sq3(A.x, A.y, Bv.x);
  o.y = sq3(Bv.y, C.x, C.y);
  ((float2*)s2)[i] = o;
}

// 2 points per thread, packed ushort cl store. XCD-affine: batch = blockIdx & 7.
__global__ void k_assign(const float* __restrict__ x, const float* __restrict__ centers,
                         unsigned char* __restrict__ cl) {
  __shared__ float4 cs[KC];
  int g = blockIdx.x;
  int b = g & 7;                    // batch -> XCD (matches update/topk mapping)
  int chunk = g >> 3;               // 0..127
  int t = threadIdx.x;
  if (t < KC) {
    float a0 = centers[(b * KC + t) * 3 + 0];
    float a1 = centers[(b * KC + t) * 3 + 1];
    float a2 = centers[(b * KC + t) * 3 + 2];
    cs[t] = make_float4(a0, a1, a2, sq3(a0, a1, a2));
  }
  __syncthreads();
  int pr = chunk * 256 + t;         // pair index within batch (points 2pr, 2pr+1)
  const float2* xb2 = (const float2*)(x + (size_t)b * N * 3);
  float2 A = xb2[3 * pr], Bv = xb2[3 * pr + 1], C = xb2[3 * pr + 2];
  float s20 = sq3(A.x, A.y, Bv.x);
  float s21 = sq3(Bv.y, C.x, C.y);
  float best0 = __int_as_float(0x7f800000), best1 = best0;
  int bi0 = 0, bi1 = 0;
  for (int k = 0; k < KC; ++k) {
    float4 cc = cs[k];
    float d0 = distf(s20, cc.w, dot3(A.x, A.y, Bv.x, cc.x, cc.y, cc.z));
    float d1 = distf(s21, cc.w, dot3(Bv.y, C.x, C.y, cc.x, cc.y, cc.z));
    if (d0 < best0) { best0 = d0; bi0 = k; }   // first-min == argmin
    if (d1 < best1) { best1 = d1; bi1 = k; }
  }
  *(unsigned short*)(cl + (size_t)b * N + 2 * pr) =
      (unsigned short)(bi0 | (bi1 << 8));
}

// one block per (b,k): find own members from cl (stable, index order),
// gather coords to LDS, lanes 0/1/2 run the three sequential fp32 chains in
// lockstep — bit-identical to np.add.at's per-cluster sequential sum.
__global__ __launch_bounds__(UPD_T)
void k_cluster_update(const float* __restrict__ x, const unsigned char* __restrict__ cl,
                      float* __restrict__ centers) {
  __shared__ unsigned short midx[RANGE];          // 32 KB
  __shared__ float bcoord[3][GBATCH + 1];         // ~24 KB, padded stride
  __shared__ int woff[NWAVES];
  __shared__ int sCnt;
  int g = blockIdx.x;
  int bk = ((g & 7) << 6) | (g >> 3);             // XCD-affine: batch = g & 7
  int b = bk >> 6, k = bk & 63;
  int t = threadIdx.x, lane = t & 63, wid = t >> 6;
  const unsigned char* clb = cl + (size_t)b * N;
  const float* xb = x + (size_t)b * N * 3;
  float acc = 0.f;      // lanes 0/1/2 of wave 0 carry x/y/z sums
  int cntAll = 0;

  for (int r = 0; r < NRANGE; ++r) {
    // 1. count matches in my contiguous 16-point segment
    const uint4* cp = (const uint4*)(clb + r * RANGE);
    uint4 v = cp[t];
    u32 wsv[4] = {v.x, v.y, v.z, v.w};
    int m = 0;
#pragma unroll
    for (int j = 0; j < PPT; ++j)
      m += (((wsv[j >> 2] >> ((j & 3) * 8)) & 255u) == (u32)k);
    // 2. block exclusive scan of per-thread counts
    int incl = m;
#pragma unroll
    for (int o = 1; o < 64; o <<= 1) {
      int u = __shfl_up(incl, o);
      if (lane >= o) incl += u;
    }
    if (lane == 63) woff[wid] = incl;
    __syncthreads();
    if (t == 0) {
      int run = 0;
      for (int w = 0; w < NWAVES; ++w) { int vv = woff[w]; woff[w] = run; run += vv; }
      sCnt = run;
    }
    __syncthreads();
    int off = woff[wid] + incl - m;
    int mcnt = sCnt;
    // 3. write member local indices in ascending order (stable)
    int base = t * PPT;
#pragma unroll
    for (int j = 0; j < PPT; ++j) {
      if (((wsv[j >> 2] >> ((j & 3) * 8)) & 255u) == (u32)k)
        midx[off++] = (unsigned short)(base + j);
    }
    __syncthreads();
    // 4. gather + lockstep serial sum, in batches
    for (int bo = 0; bo < mcnt; bo += GBATCH) {
      int bn = min(GBATCH, mcnt - bo);
      for (int i = t; i < bn; i += UPD_T) {
        int li = midx[bo + i];
        size_t src = ((size_t)(r * RANGE + li)) * 3;
        bcoord[0][i] = xb[src];
        bcoord[1][i] = xb[src + 1];
        bcoord[2][i] = xb[src + 2];
      }
      __syncthreads();
      if (wid == 0 && lane < 3) {
        const float* mb = &bcoord[lane][0];     // per-lane base, bank-decorrelated
        for (int i = 0; i < bn; ++i) acc = __fadd_rn(acc, mb[i]);
      }
      __syncthreads();
    }
    cntAll += mcnt;
    __syncthreads();
  }
  if (wid == 0 && lane < 3)
    centers[bk * 3 + lane] = __fdiv_rn(acc, (float)cntAll);
}

// exact top-M (smallest distance, lower-index tiebreak) per (b,center).
// Sampled-threshold selection (exact): thrK = exact M-th smallest key of the
// first SAMPLE points (>= true M-th key since sample is a subset). One full-N
// scan collects key <= thrK (expected ~8*M); bitonic sort -> first M.
// Overflow (data-dependent, deterministic) falls back to full byte-radix.
__global__ __launch_bounds__(TOPK_T)
void k_query_topk(const float* __restrict__ x, const float* __restrict__ s2g,
                  const float* __restrict__ centers, float* __restrict__ neighbor) {
  __shared__ u32 whist[NWAVES * HPAD];   // per-wave byte histograms (sample)
  __shared__ u32 hist[256];
  __shared__ u32 skeys[SCAP];            // sample same-byte candidate keys
  __shared__ u64 candList[CAP];
  __shared__ u64 lessList[M];
  __shared__ u32 eqList[256];
  __shared__ u32 sPrefix;
  __shared__ int sNeed, sCntBin;
  __shared__ int cntCand, cntLess, cntEq;
  __shared__ float sc0, sc1, sc2, sd2;

  int g = blockIdx.x;
  int bk = ((g & 7) << 6) | (g >> 3);   // batch = g & 7 -> XCD-affine
  int b = bk >> 6;
  int t = threadIdx.x;
  int wid = t >> 6;
  if (t == 0) {
    float c0 = centers[bk * 3], c1 = centers[bk * 3 + 1], c2 = centers[bk * 3 + 2];
    sc0 = c0; sc1 = c1; sc2 = c2; sd2 = sq3(c0, c1, c2);
    cntCand = 0; cntLess = 0; cntEq = 0;
  }
  for (int i = t; i < NWAVES * HPAD; i += TOPK_T) whist[i] = 0;
  __syncthreads();
  float c0 = sc0, c1 = sc1, c2 = sc2, d2 = sd2;
  const float* xb = x + (size_t)b * N * 3;
  const float2* xb2 = (const float2*)xb;
  const float2* s2b2 = (const float2*)(s2g + (size_t)b * N);

  // ---- phase A: byte histogram of the SAMPLE prefix (per-wave atomics) ----
  for (int p = t; p < SAMPLE / 2; p += TOPK_T) {
    float2 A = xb2[3 * p], Bv = xb2[3 * p + 1], C = xb2[3 * p + 2];
    float2 s2p = s2b2[p];
    float d0 = distf(s2p.x, d2, dot3(A.x, A.y, Bv.x, c0, c1, c2));
    float d1 = distf(s2p.y, d2, dot3(Bv.y, C.x, C.y, c0, c1, c2));
    atomicAdd(&whist[wid * HPAD + (fkey(d0) >> 24)], 1u);
    atomicAdd(&whist[wid * HPAD + (fkey(d1) >> 24)], 1u);
  }
  __syncthreads();
  if (t < 256) {
    u32 s = 0;
#pragma unroll
    for (int w = 0; w < NWAVES; ++w) s += whist[w * HPAD + t];
    hist[t] = s;
  }
  __syncthreads();
  if (t == 0) {
    int cum = 0;
    for (int bin = 0; bin < 256; ++bin) {
      int c = (int)hist[bin];
      if (cum + c >= M) { sPrefix = (u32)bin; sNeed = M - cum; sCntBin = c; break; }
      cum += c;
    }
  }
  __syncthreads();
  u32 selByte = sPrefix;
  int needEq = sNeed;      // rank of threshold within the selByte bin
  int cntBin = sCntBin;

  u32 thrK;
  if (cntBin <= SCAP) {
    // ---- phase B: collect sample keys in the selByte bin ----
    for (int p = t; p < SAMPLE / 2; p += TOPK_T) {
      float2 A = xb2[3 * p], Bv = xb2[3 * p + 1], C = xb2[3 * p + 2];
      float2 s2p = s2b2[p];
      float d0 = distf(s2p.x, d2, dot3(A.x, A.y, Bv.x, c0, c1, c2));
      float d1 = distf(s2p.y, d2, dot3(Bv.y, C.x, C.y, c0, c1, c2));
      u32 k0 = fkey(d0), k1 = fkey(d1);
      if ((k0 >> 24) == selByte) skeys[atomicAdd(&cntEq, 1)] = k0;
      if ((k1 >> 24) == selByte) skeys[atomicAdd(&cntEq, 1)] = k1;
    }
    __syncthreads();
    int ne = cntEq;   // == cntBin
    // ---- phase C: in-LDS radix refinement (bytes 2,1,0) -> exact sample M-th key ----
    u32 prefix = selByte << 24;
    int need = needEq;
    for (int sh = 16; sh >= 0; sh -= 8) {
      for (int i = t; i < 256; i += TOPK_T) hist[i] = 0;
      __syncthreads();
      for (int i = t; i < ne; i += TOPK_T) {
        u32 kk = skeys[i];
        if ((kk >> (sh + 8)) == (prefix >> (sh + 8)))
          atomicAdd(&hist[(kk >> sh) & 255u], 1u);
      }
      __syncthreads();
      if (t == 0) {
        int cum = 0;
        for (int bin = 0; bin < 256; ++bin) {
          int c = (int)hist[bin];
          if (cum + c >= need) { sPrefix = prefix | ((u32)bin << sh); sNeed = need - cum; break; }
          cum += c;
        }
      }
      __syncthreads();
      prefix = sPrefix; need = sNeed;
      __syncthreads();
    }
    thrK = prefix;          // exact M-th smallest key of the sample
  } else {
    thrK = (selByte << 24) | 0x00FFFFFFu;   // loose upper bound; may overflow -> fallback
  }

  // ---- phase D: single full-N scan, collect key <= thrK ----
  for (int p = t; p < N / 2; p += TOPK_T) {
    float2 A = xb2[3 * p], Bv = xb2[3 * p + 1], C = xb2[3 * p + 2];
    float2 s2p = s2b2[p];
    float d0 = distf(s2p.x, d2, dot3(A.x, A.y, Bv.x, c0, c1, c2));
    float d1 = distf(s2p.y, d2, dot3(Bv.y, C.x, C.y, c0, c1, c2));
    u32 k0 = fkey(d0), k1 = fkey(d1);
    if (k0 <= thrK) {
      int q = atomicAdd(&cntCand, 1);
      if (q < CAP) candList[q] = ((u64)k0 << 32) | (u32)(2 * p);
    }
    if (k1 <= thrK) {
      int q = atomicAdd(&cntCand, 1);
      if (q < CAP) candList[q] = ((u64)k1 << 32) | (u32)(2 * p + 1);
    }
  }
  __syncthreads();
  int cc = cntCand;

  if (cc <= CAP) {
    // ---- phase E: bitonic sort candidates by (key, idx), emit first M ----
    int P = 1; while (P < cc) P <<= 1;
    if (P < M) P = M;
    for (int i = t; i < P; i += TOPK_T) if (i >= cc) candList[i] = ~0ull;
    __syncthreads();
    for (int ksz = 2; ksz <= P; ksz <<= 1) {
      for (int j = ksz >> 1; j > 0; j >>= 1) {
        for (int idx = t; idx < P; idx += TOPK_T) {
          int ixj = idx ^ j;
          if (ixj > idx) {
            u64 a = candList[idx], bb = candList[ixj];
            bool up = ((idx & ksz) == 0);
            if (up ? (a > bb) : (a < bb)) { candList[idx] = bb; candList[ixj] = a; }
          }
        }
        __syncthreads();
      }
    }
    if (t < M) {
      int idx = (int)(candList[t] & 0xFFFFFFFFu);
      size_t src = ((size_t)b * N + idx) * 3;
      size_t dst = ((size_t)bk * M + t) * 3;
      neighbor[dst]     = x[src];
      neighbor[dst + 1] = x[src + 1];
      neighbor[dst + 2] = x[src + 2];
    }
    return;
  }

  // ---- fallback: full byte-radix over N (bit-identical, rare) ----
  u32 prefix = 0;
  int need = M;
  for (int r = 3; r >= 0; --r) {
    for (int i = t; i < 256; i += TOPK_T) hist[i] = 0;
    __syncthreads();
    int sh = r * 8;
    for (int n = t; n < N; n += TOPK_T) {
      float x0 = xb[n * 3], x1 = xb[n * 3 + 1], x2 = xb[n * 3 + 2];
      float d = distf(sq3(x0, x1, x2), d2, dot3(x0, x1, x2, c0, c1, c2));
      u32 key = fkey(d);
      bool ok = (r == 3) || ((key >> (sh + 8)) == (prefix >> (sh + 8)));
      if (ok) atomicAdd(&hist[(key >> sh) & 255u], 1u);
    }
    __syncthreads();
    if (t == 0) {
      int cum = 0;
      for (int bin = 0; bin < 256; ++bin) {
        int c = (int)hist[bin];
        if (cum + c >= need) { sPrefix = prefix | ((u32)bin << sh); sNeed = need - cum; break; }
        cum += c;
      }
    }
    __syncthreads();
    prefix = sPrefix; need = sNeed;
    __syncthreads();
  }
  u32 K128 = prefix;   // exact key of the M-th smallest distance

  if (t == 0) { cntLess = 0; cntEq = 0; }
  __syncthreads();
  for (int n = t; n < N; n += TOPK_T) {
    float x0 = xb[n * 3], x1 = xb[n * 3 + 1], x2 = xb[n * 3 + 2];
    float d = distf(sq3(x0, x1, x2), d2, dot3(x0, x1, x2, c0, c1, c2));
    u32 key = fkey(d);
    if (key < K128) {
      int p = atomicAdd(&cntLess, 1);
      if (p < M) lessList[p] = ((u64)key << 32) | (u32)n;
    } else if (key == K128) {
      int p = atomicAdd(&cntEq, 1);
      if (p < 256) eqList[p] = (u32)n;
    }
  }
  __syncthreads();
  int nl = cntLess;
  int ne2 = cntEq;
  for (int i = t; i < M; i += TOPK_T) if (i >= nl) lessList[i] = ~0ull;
  for (int i = t; i < 256; i += TOPK_T) if (i >= ne2) eqList[i] = 0xFFFFFFFFu;
  __syncthreads();

  for (int ksz = 2; ksz <= M; ksz <<= 1) {
    for (int j = ksz >> 1; j > 0; j >>= 1) {
      for (int idx = t; idx < M; idx += TOPK_T) {
        int ixj = idx ^ j;
        if (ixj > idx) {
          u64 a = lessList[idx], bb = lessList[ixj];
          bool up = ((idx & ksz) == 0);
          if (up ? (a > bb) : (a < bb)) { lessList[idx] = bb; lessList[ixj] = a; }
        }
      }
      __syncthreads();
    }
  }
  for (int ksz = 2; ksz <= 256; ksz <<= 1) {
    for (int j = ksz >> 1; j > 0; j >>= 1) {
      for (int idx = t; idx < 256; idx += TOPK_T) {
        int ixj = idx ^ j;
        if (ixj > idx) {
          u32 a = eqList[idx], bb = eqList[ixj];
          bool up = ((idx & ksz) == 0);
          if (up ? (a > bb) : (a < bb)) { eqList[idx] = bb; eqList[ixj] = a; }
        }
      }
      __syncthreads();
    }
  }

  if (t < M) {
    int idx = (t < nl) ? (int)(lessList[t] & 0xFFFFFFFFu) : (int)eqList[t - nl];
    size_t src = ((size_t)b * N + idx) * 3;
    size_t dst = ((size_t)bk * M + t) * 3;
    neighbor[dst]     = x[src];
    neighbor[dst + 1] = x[src + 1];
    neighbor[dst + 2] = x[src + 2];
  }
}

__global__ void k_fps(const float* __restrict__ neighbor, const int* __restrict__ farthest0,
                      const float* __restrict__ centers, float* __restrict__ out) {
  __shared__ float px[M], py[M], pz[M];
  __shared__ float wv[2];
  __shared__ int wi[2];
  int bg = blockIdx.x;  // b*64 + g
  int b = bg >> 6, g = bg & 63;
  int t = threadIdx.x;  // 128 threads = M
  // fused centers copy (blocks 0..11 handle 1536 floats)
  {
    int i = bg * 128 + t;
    if (i < B * KC * 3) out[B * 4096 * 3 + i] = centers[i];
  }
  size_t src = ((size_t)bg * M + t) * 3;
  float mx = neighbor[src], my = neighbor[src + 1], mz = neighbor[src + 2];
  px[t] = mx; py[t] = my; pz[t] = mz;
  int far = farthest0[bg];
  float dist = 1e10f;
  __syncthreads();
  for (int s = 0; s < S; ++s) {
    // record current farthest (scan outputs OLD carry), then update
    if (t == far) {
      size_t dst = ((size_t)b * 4096 + g * 64 + s) * 3;
      out[dst] = mx; out[dst + 1] = my; out[dst + 2] = mz;
    }
    float cx = px[far], cy = py[far], cz = pz[far];
    float dx = __fsub_rn(mx, cx), dy = __fsub_rn(my, cy), dz = __fsub_rn(mz, cz);
    float d = sq3(dx, dy, dz);
    dist = fminf(dist, d);
    float v = dist;
    int i = t;
#pragma unroll
    for (int off = 1; off < 64; off <<= 1) {
      float ov = __shfl_xor(v, off);
      int oi = __shfl_xor(i, off);
      if (ov > v || (ov == v && oi < i)) { v = ov; i = oi; }
    }
    int wid = t >> 6;
    if ((t & 63) == 0) { wv[wid] = v; wi[wid] = i; }
    __syncthreads();
    float v0 = wv[0]; int i0 = wi[0];
    float v1 = wv[1]; int i1 = wi[1];
    far = (v1 > v0 || (v1 == v0 && i1 < i0)) ? i1 : i0;  // first-occurrence argmax
    __syncthreads();
  }
}

extern "C" void kernel_launch(void* const* d_in, const int* in_sizes, int n_in,
                              void* d_out, int out_size, void* d_ws, size_t ws_size,
                              hipStream_t stream) {
  const float* x = (const float*)d_in[0];
  const int* farthest0 = (const int*)d_in[1];
  float* out = (float*)d_out;

  char* w = (char*)d_ws;
  float* centers         = (float*)(w);                       // 6144 B
  unsigned char* cl      = (unsigned char*)(w + 8192);        // 524288 B
  float* s2              = (float*)(w + 8192 + 524288);       // 2097152 B
  float* neighbor        = (float*)(w + 8192 + 524288 + 2097152); // 786432 B
  // total ws use ≈ 3.4 MB

  k_init_centers<<<6, 256, 0, stream>>>(x, centers);
  k_s2<<<B * N / 2 / 256, 256, 0, stream>>>(x, s2);
  for (int it = 0; it < NITER; ++it) {
    k_assign<<<B * 128, 256, 0, stream>>>(x, centers, cl);
    k_cluster_update<<<B * KC, UPD_T, 0, stream>>>(x, cl, centers);
  }
  k_query_topk<<<B * KC, TOPK_T, 0, stream>>>(x, s2, centers, neighbor);
  k_fps<<<B * KC, M, 0, stream>>>(neighbor, farthest0, centers, out);
}